// Round 5
// baseline (272.599 us; speedup 1.0000x reference)
//
#include <hip/hip_runtime.h>
#include <hip/hip_bf16.h>
#include <stdint.h>

#define D_DIM 512
#define B_CTX 512
#define M_MEM 65536
#define BM 128
#define BB 128
#define BK 32
#define GBK 32               // K-step of the fast bf16 GEMM (counted-vmcnt pipeline)
#define NIT (D_DIM / GBK)    // 16 K-steps
#define LDSPAD 40            // 80 B row pitch for legacy fallback kernel
#define DELTA_COS 2.5e-3f    // ~35 sigma of bf16 cosine noise, scale-invariant
#define LISTCAP 2048
#define CVT_MEM_BLOCKS (M_MEM / 32)            // 2048: 4 waves x 8 rows each
#define CVT_BLOCKS (CVT_MEM_BLOCKS + B_CTX / 32)

typedef __attribute__((ext_vector_type(8))) short short8;   // 8 bf16 (4 VGPR)
typedef __attribute__((ext_vector_type(4))) float floatx4;  // MFMA accumulator

__device__ __forceinline__ uint32_t f32_order(float s) {    // monotone f32->u32
    uint32_t u = __float_as_uint(s);
    return (u & 0x80000000u) ? ~u : (u | 0x80000000u);
}
__device__ __forceinline__ float f32_unorder(uint32_t v) {
    uint32_t u = (v & 0x80000000u) ? (v & 0x7FFFFFFFu) : ~v;
    return __uint_as_float(u);
}
__device__ __forceinline__ uint32_t pack_bf16_rtn(float a, float b) {
    uint32_t ua = __float_as_uint(a) + 0x8000u;
    uint32_t ub = __float_as_uint(b) + 0x8000u;
    return (ua >> 16) | (ub & 0xFFFF0000u);
}

// async global->LDS, 16B per lane. LDS dest is WAVE-UNIFORM base; HW adds lane*16.
typedef const __attribute__((address_space(1))) void gv_t;
typedef __attribute__((address_space(3))) void lv_t;
__device__ __forceinline__ void gload_lds16(const uint16_t* g, uint16_t* l) {
    __builtin_amdgcn_global_load_lds((gv_t*)g, (lv_t*)l, 16, 0, 0);
}

// ---------------- kernel 0: dtype probe ----------------
__global__ void detect_init(const uint32_t* __restrict__ mem_raw,
                            uint32_t* __restrict__ flag) {
    __shared__ int cnt;
    if (threadIdx.x == 0) cnt = 0;
    __syncthreads();
    int s = 0;
    #pragma unroll
    for (int i = 0; i < 8; ++i) {
        uint32_t u = mem_raw[threadIdx.x * 8 + i];
        uint32_t e = (u >> 7) & 0xFFu;   // exponent of LOW bf16 half
        s += (e >= 96u && e <= 144u) ? 1 : 0;
    }
    atomicAdd(&cnt, s);
    __syncthreads();
    if (threadIdx.x == 0) *flag = (cnt > 256) ? 1u : 0u;   // 1 == bf16 inputs
}

// ---- kernel A: one-pass convert. mem -> bf16(mem * 1/|mem|), ctx -> bf16(ctx) ----
__global__ __launch_bounds__(256) void convert_scale(const void* __restrict__ ctxv,
                                                     const void* __restrict__ memv,
                                                     const uint32_t* __restrict__ flag,
                                                     uint16_t* __restrict__ mem_s,
                                                     uint16_t* __restrict__ ctx_b) {
    const bool isbf = (*flag != 0u);
    const int lane = threadIdx.x & 63;
    const int w = threadIdx.x >> 6;
    if (blockIdx.x < CVT_MEM_BLOCKS) {
        const int gw = blockIdx.x * 4 + w;           // 0..8191
        #pragma unroll
        for (int i = 0; i < 8; ++i) {
            const int r = gw * 8 + i;                // 0..65535
            float x[8];
            if (isbf) {
                uint4 v = *((const uint4*)((const uint16_t*)memv + (size_t)r * D_DIM) + lane);
                uint32_t ww[4] = {v.x, v.y, v.z, v.w};
                #pragma unroll
                for (int j = 0; j < 4; ++j) {
                    x[2 * j]     = __uint_as_float(ww[j] << 16);
                    x[2 * j + 1] = __uint_as_float(ww[j] & 0xFFFF0000u);
                }
            } else {
                const float4* p = (const float4*)((const float*)memv + (size_t)r * D_DIM) + lane * 2;
                float4 a = p[0], bq = p[1];
                x[0] = a.x; x[1] = a.y; x[2] = a.z; x[3] = a.w;
                x[4] = bq.x; x[5] = bq.y; x[6] = bq.z; x[7] = bq.w;
            }
            float nsq = 0.f;
            #pragma unroll
            for (int j = 0; j < 8; ++j) nsq = fmaf(x[j], x[j], nsq);
            #pragma unroll
            for (int o = 32; o; o >>= 1) nsq += __shfl_xor(nsq, o, 64);
            const float invn = rsqrtf(fmaxf(nsq, 1e-12f));
            uint4 ov;
            ov.x = pack_bf16_rtn(x[0] * invn, x[1] * invn);
            ov.y = pack_bf16_rtn(x[2] * invn, x[3] * invn);
            ov.z = pack_bf16_rtn(x[4] * invn, x[5] * invn);
            ov.w = pack_bf16_rtn(x[6] * invn, x[7] * invn);
            *((uint4*)(mem_s + (size_t)r * D_DIM) + lane) = ov;
        }
    } else {
        const int gw = (blockIdx.x - CVT_MEM_BLOCKS) * 4 + w;   // 0..63
        #pragma unroll
        for (int i = 0; i < 8; ++i) {
            const int r = gw * 8 + i;                // 0..511
            uint4 ov;
            if (isbf) {
                ov = *((const uint4*)((const uint16_t*)ctxv + (size_t)r * D_DIM) + lane);
            } else {
                const float4* p = (const float4*)((const float*)ctxv + (size_t)r * D_DIM) + lane * 2;
                float4 a = p[0], bq = p[1];
                ov.x = pack_bf16_rtn(a.x, a.y);
                ov.y = pack_bf16_rtn(a.z, a.w);
                ov.z = pack_bf16_rtn(bq.x, bq.y);
                ov.w = pack_bf16_rtn(bq.z, bq.w);
            }
            *((uint4*)(ctx_b + (size_t)r * D_DIM) + lane) = ov;
        }
    }
}

// ---- kernel B: pure-bf16 MFMA GEMM, counted-vmcnt pipeline (T3+T4):
// STAGE(next) stays IN FLIGHT across the barrier (s_waitcnt vmcnt(4), never 0
// in steady state); trailing raw s_barrier + lgkmcnt(0) protects buffer reuse
// without draining the prefetch. T2 swizzle via pre-swizzled global source +
// swizzled ds_read (rule #21). XCD-chunked block remap for A-panel L2 reuse. ----
#define STAGE(buf, kofs)                                                          \
    do {                                                                          \
        gload_lds16(ga0 + (kofs), &at[buf][0][0] + (size_t)((w << 6)) * 8);       \
        gload_lds16(ga1 + (kofs), &at[buf][0][0] + (size_t)(256 + (w << 6)) * 8); \
        gload_lds16(gb0 + (kofs), &bt[buf][0][0] + (size_t)((w << 6)) * 8);       \
        gload_lds16(gb1 + (kofs), &bt[buf][0][0] + (size_t)(256 + (w << 6)) * 8); \
    } while (0)

__global__ __launch_bounds__(256, 4) void score_mfma(const uint16_t* __restrict__ A,   // mem_s [M][512]
                                                     const uint16_t* __restrict__ Bc,  // ctx_b [B][512]
                                                     uint32_t* __restrict__ tmax,
                                                     int coarse) {
    __shared__ __align__(16) uint16_t at[2][BM][GBK];   // 2 x 8KB, LINEAR dest
    __shared__ __align__(16) uint16_t bt[2][BB][GBK];   // 2 x 8KB
    __shared__ uint32_t s_gbest[8][BB];

    // XCD-chunked remap: HW round-robins flat id across 8 XCDs (h&7). Map so each
    // XCD owns a contiguous strip of m-panels covering all 4 b-panels -> the 4
    // blocks sharing an A-tile share one L2, dispatched in consecutive rounds.
    const int h  = blockIdx.y * gridDim.x + blockIdx.x;   // 0..2047
    const int v  = (h & 7) * 256 + (h >> 3);
    const int bxp = v & 3;                                // b-panel 0..3
    const int byp = v >> 2;                               // m-panel 0..511

    const int t    = threadIdx.x;
    const int b0   = bxp * BB;
    const int m0   = byp * BM;
    const int lane = t & 63;
    const int w    = t >> 6;
    const int wm   = w >> 1;
    const int wb   = w & 1;
    const int quad = lane >> 4;
    const int l15  = lane & 15;
    const int srow = t >> 2;          // 0..63 (chunk row, +64 for second issue)
    // T2 swizzle for 64B row pitch: 16B chunk-in-row (0..3) XOR ((row>>1)&3).
    // Stage pulls global chunk (r, j^f(r)) into linear LDS chunk (r, j); read
    // applies the same XOR -> involution; conflict-free (2-way residual, m136).
    const int scol_sw = (((t & 3) ^ ((t >> 3) & 3)) << 3);   // staging: element col
    const int rc = ((quad ^ ((l15 >> 1) & 3)) << 3);         // read: element col

    const uint16_t* ga0 = A  + (size_t)(m0 + srow) * D_DIM + scol_sw;
    const uint16_t* ga1 = A  + (size_t)(m0 + srow + 64) * D_DIM + scol_sw;
    const uint16_t* gb0 = Bc + (size_t)(b0 + srow) * D_DIM + scol_sw;
    const uint16_t* gb1 = Bc + (size_t)(b0 + srow + 64) * D_DIM + scol_sw;

    floatx4 acc[4][4];
    #pragma unroll
    for (int i = 0; i < 4; ++i)
        #pragma unroll
        for (int j = 0; j < 4; ++j)
            acc[i][j] = (floatx4){0.f, 0.f, 0.f, 0.f};

    // prologue: stage tile 0 (4 loads/wave outstanding)
    STAGE(0, 0);

    #pragma unroll
    for (int it = 0; it < NIT; ++it) {
        const int cur = it & 1;
        if (it < NIT - 1) STAGE(cur ^ 1, (it + 1) * GBK);   // +4 loads, in flight
        // wait ONLY for the current tile (oldest 4); next tile stays in flight.
        if (it < NIT - 1) asm volatile("s_waitcnt vmcnt(4)" ::: "memory");
        else              asm volatile("s_waitcnt vmcnt(0)" ::: "memory");
        __builtin_amdgcn_sched_barrier(0);
        __builtin_amdgcn_s_barrier();
        __builtin_amdgcn_sched_barrier(0);

        short8 af[4], bg[4];
        #pragma unroll
        for (int i = 0; i < 4; ++i)
            af[i] = *(const short8*)&at[cur][wm * 64 + i * 16 + l15][rc];
        #pragma unroll
        for (int j = 0; j < 4; ++j)
            bg[j] = *(const short8*)&bt[cur][wb * 64 + j * 16 + l15][rc];
        #pragma unroll
        for (int i = 0; i < 4; ++i)
            #pragma unroll
            for (int j = 0; j < 4; ++j)
                acc[i][j] = __builtin_amdgcn_mfma_f32_16x16x32_bf16(af[i], bg[j], acc[i][j], 0, 0, 0);

        if (it < NIT - 1) {
            // trailing barrier: buf[cur] may be re-staged next iteration. Drain
            // ds_reads (lgkmcnt) but NOT vmcnt (prefetch stays in flight).
            __builtin_amdgcn_sched_barrier(0);
            asm volatile("s_waitcnt lgkmcnt(0)" ::: "memory");
            __builtin_amdgcn_s_barrier();
            __builtin_amdgcn_sched_barrier(0);
        }
    }

    // group epilogue: frag i == 16-row group (wm*4+i). Cross-quad shuffle, no atomics.
    #pragma unroll
    for (int i = 0; i < 4; ++i)
        #pragma unroll
        for (int j = 0; j < 4; ++j) {
            uint32_t k = 0;
            #pragma unroll
            for (int r = 0; r < 4; ++r) {
                uint32_t kk = f32_order(acc[i][j][r]);   // already cos * |ctx|
                k = kk > k ? kk : k;
            }
            uint32_t o1 = __shfl_xor(k, 16, 64); k = o1 > k ? o1 : k;
            uint32_t o2 = __shfl_xor(k, 32, 64); k = o2 > k ? o2 : k;
            if (quad == 0) s_gbest[wm * 4 + i][wb * 64 + j * 16 + l15] = k;
        }
    __syncthreads();

    if (!coarse) {
        const int G0 = byp * 8;
        for (int e = t; e < 8 * BB; e += 256) {
            const int col = e >> 3, g = e & 7;
            tmax[(size_t)(b0 + col) * 4096 + G0 + g] = s_gbest[g][col];
        }
    } else {
        if (t < BB) {
            uint32_t k = s_gbest[0][t];
            #pragma unroll
            for (int g = 1; g < 8; ++g) k = s_gbest[g][t] > k ? s_gbest[g][t] : k;
            tmax[(size_t)(b0 + t) * 512 + byp] = k;
        }
    }
}

// ---- legacy kernel 1 (fallback when workspace too small for bf16 copies) ----
__global__ __launch_bounds__(256) void score_phase1(const void* __restrict__ ctxv,
                                                    const void* __restrict__ memv,
                                                    const uint32_t* __restrict__ flag,
                                                    uint32_t* __restrict__ tmax,
                                                    int coarse) {
    __shared__ __align__(16) uint16_t at[BM][LDSPAD];
    __shared__ __align__(16) uint16_t bt[BB][LDSPAD];
    __shared__ float s_nsq[BM];
    __shared__ uint32_t s_gbest[8][BB];

    const int t    = threadIdx.x;
    const int b0   = blockIdx.x * BB;
    const int m0   = blockIdx.y * BM;
    const int lane = t & 63;
    const int w    = t >> 6;
    const int wm   = w >> 1;
    const int wb   = w & 1;
    const int quad = lane >> 4;
    const int l15  = lane & 15;
    const int srow = t >> 2;
    const int scol = (t & 3) * 8;

    floatx4 acc[4][4];
    #pragma unroll
    for (int i = 0; i < 4; ++i)
        #pragma unroll
        for (int j = 0; j < 4; ++j)
            acc[i][j] = (floatx4){0.f, 0.f, 0.f, 0.f};

    float nsq0 = 0.f, nsq1 = 0.f;
    const bool isbf = (*flag != 0u);

    for (int k0 = 0; k0 < D_DIM; k0 += BK) {
        __syncthreads();
        if (isbf) {
            const uint16_t* mp = (const uint16_t*)memv;
            const uint16_t* cp = (const uint16_t*)ctxv;
            uint4 va0 = *(const uint4*)(mp + (size_t)(m0 + srow) * D_DIM + k0 + scol);
            uint4 va1 = *(const uint4*)(mp + (size_t)(m0 + srow + 64) * D_DIM + k0 + scol);
            uint4 vb0 = *(const uint4*)(cp + (size_t)(b0 + srow) * D_DIM + k0 + scol);
            uint4 vb1 = *(const uint4*)(cp + (size_t)(b0 + srow + 64) * D_DIM + k0 + scol);
            *(uint4*)&at[srow][scol] = va0;
            *(uint4*)&at[srow + 64][scol] = va1;
            *(uint4*)&bt[srow][scol] = vb0;
            *(uint4*)&bt[srow + 64][scol] = vb1;
            uint32_t wa0[4] = {va0.x, va0.y, va0.z, va0.w};
            uint32_t wa1[4] = {va1.x, va1.y, va1.z, va1.w};
            #pragma unroll
            for (int i = 0; i < 4; ++i) {
                float a = __uint_as_float(wa0[i] << 16);
                float b = __uint_as_float(wa0[i] & 0xFFFF0000u);
                nsq0 = fmaf(a, a, nsq0); nsq0 = fmaf(b, b, nsq0);
                float c = __uint_as_float(wa1[i] << 16);
                float d = __uint_as_float(wa1[i] & 0xFFFF0000u);
                nsq1 = fmaf(c, c, nsq1); nsq1 = fmaf(d, d, nsq1);
            }
        } else {
            const float* mp = (const float*)memv;
            const float* cp = (const float*)ctxv;
            const float4* pa0 = (const float4*)(mp + (size_t)(m0 + srow) * D_DIM + k0 + scol);
            const float4* pa1 = (const float4*)(mp + (size_t)(m0 + srow + 64) * D_DIM + k0 + scol);
            const float4* pb0 = (const float4*)(cp + (size_t)(b0 + srow) * D_DIM + k0 + scol);
            const float4* pb1 = (const float4*)(cp + (size_t)(b0 + srow + 64) * D_DIM + k0 + scol);
            float4 a0 = pa0[0], a1 = pa0[1], a2 = pa1[0], a3 = pa1[1];
            float4 c0 = pb0[0], c1 = pb0[1], c2 = pb1[0], c3 = pb1[1];
            uint4 va0 = {pack_bf16_rtn(a0.x, a0.y), pack_bf16_rtn(a0.z, a0.w),
                         pack_bf16_rtn(a1.x, a1.y), pack_bf16_rtn(a1.z, a1.w)};
            uint4 va1 = {pack_bf16_rtn(a2.x, a2.y), pack_bf16_rtn(a2.z, a2.w),
                         pack_bf16_rtn(a3.x, a3.y), pack_bf16_rtn(a3.z, a3.w)};
            uint4 vb0 = {pack_bf16_rtn(c0.x, c0.y), pack_bf16_rtn(c0.z, c0.w),
                         pack_bf16_rtn(c1.x, c1.y), pack_bf16_rtn(c1.z, c1.w)};
            uint4 vb1 = {pack_bf16_rtn(c2.x, c2.y), pack_bf16_rtn(c2.z, c2.w),
                         pack_bf16_rtn(c3.x, c3.y), pack_bf16_rtn(c3.z, c3.w)};
            *(uint4*)&at[srow][scol] = va0;
            *(uint4*)&at[srow + 64][scol] = va1;
            *(uint4*)&bt[srow][scol] = vb0;
            *(uint4*)&bt[srow + 64][scol] = vb1;
            nsq0 = fmaf(a0.x, a0.x, nsq0); nsq0 = fmaf(a0.y, a0.y, nsq0);
            nsq0 = fmaf(a0.z, a0.z, nsq0); nsq0 = fmaf(a0.w, a0.w, nsq0);
            nsq0 = fmaf(a1.x, a1.x, nsq0); nsq0 = fmaf(a1.y, a1.y, nsq0);
            nsq0 = fmaf(a1.z, a1.z, nsq0); nsq0 = fmaf(a1.w, a1.w, nsq0);
            nsq1 = fmaf(a2.x, a2.x, nsq1); nsq1 = fmaf(a2.y, a2.y, nsq1);
            nsq1 = fmaf(a2.z, a2.z, nsq1); nsq1 = fmaf(a2.w, a2.w, nsq1);
            nsq1 = fmaf(a3.x, a3.x, nsq1); nsq1 = fmaf(a3.y, a3.y, nsq1);
            nsq1 = fmaf(a3.z, a3.z, nsq1); nsq1 = fmaf(a3.w, a3.w, nsq1);
        }
        __syncthreads();

        short8 af[4], bg[4];
        #pragma unroll
        for (int i = 0; i < 4; ++i)
            af[i] = *(const short8*)&at[wm * 64 + i * 16 + l15][quad * 8];
        #pragma unroll
        for (int j = 0; j < 4; ++j)
            bg[j] = *(const short8*)&bt[wb * 64 + j * 16 + l15][quad * 8];

        #pragma unroll
        for (int i = 0; i < 4; ++i)
            #pragma unroll
            for (int j = 0; j < 4; ++j)
                acc[i][j] = __builtin_amdgcn_mfma_f32_16x16x32_bf16(af[i], bg[j], acc[i][j], 0, 0, 0);
    }

    nsq0 += __shfl_xor(nsq0, 1, 64); nsq0 += __shfl_xor(nsq0, 2, 64);
    nsq1 += __shfl_xor(nsq1, 1, 64); nsq1 += __shfl_xor(nsq1, 2, 64);
    __syncthreads();
    if ((t & 3) == 0) { s_nsq[srow] = nsq0; s_nsq[srow + 64] = nsq1; }
    __syncthreads();

    float invn[4][4];
    #pragma unroll
    for (int i = 0; i < 4; ++i)
        #pragma unroll
        for (int r = 0; r < 4; ++r)
            invn[i][r] = rsqrtf(fmaxf(s_nsq[wm * 64 + i * 16 + quad * 4 + r], 1e-12f));

    #pragma unroll
    for (int i = 0; i < 4; ++i)
        #pragma unroll
        for (int j = 0; j < 4; ++j) {
            uint32_t k = 0;
            #pragma unroll
            for (int r = 0; r < 4; ++r) {
                uint32_t kk = f32_order(acc[i][j][r] * invn[i][r]);
                k = kk > k ? kk : k;
            }
            uint32_t o1 = __shfl_xor(k, 16, 64); k = o1 > k ? o1 : k;
            uint32_t o2 = __shfl_xor(k, 32, 64); k = o2 > k ? o2 : k;
            if (quad == 0) s_gbest[wm * 4 + i][wb * 64 + j * 16 + l15] = k;
        }
    __syncthreads();

    if (!coarse) {
        const int G0 = blockIdx.y * 8;
        for (int e = t; e < 8 * BB; e += 256) {
            const int col = e >> 3, g = e & 7;
            tmax[(size_t)(b0 + col) * 4096 + G0 + g] = s_gbest[g][col];
        }
    } else {
        if (t < BB) {
            uint32_t k = s_gbest[0][t];
            #pragma unroll
            for (int g = 1; g < 8; ++g) k = s_gbest[g][t] > k ? s_gbest[g][t] : k;
            tmax[(size_t)(b0 + t) * 512 + blockIdx.y] = k;
        }
    }
}

// ---------------- kernel 2: exact fp64 rescore of candidate groups + gather ----------------
__global__ __launch_bounds__(256) void phase2(const void* __restrict__ ctxv,
                                              const void* __restrict__ memv,
                                              const uint32_t* __restrict__ flag,
                                              const uint32_t* __restrict__ tmax,
                                              void* __restrict__ outv,
                                              int ngrp, int gshift) {
    __shared__ float s_ctx[D_DIM];
    __shared__ int s_list[LISTCAP];
    __shared__ int s_cnt;
    __shared__ uint32_t s_red[4];
    __shared__ float s_cn[4];
    __shared__ double s_d[4], s_n[4];
    __shared__ int s_m[4];
    __shared__ int s_bestm;

    const int b = blockIdx.x;
    const int t = threadIdx.x;
    const int lane = t & 63;
    const int w = t >> 6;
    const bool isbf = (*flag != 0u);
    const int gmask = (1 << gshift) - 1;

    if (t == 0) s_cnt = 0;
    if (isbf) {
        if (t < 64) {
            uint4 v = *((const uint4*)((const uint16_t*)ctxv + (size_t)b * D_DIM) + t);
            uint32_t ww[4] = {v.x, v.y, v.z, v.w};
            #pragma unroll
            for (int i = 0; i < 4; ++i) {
                s_ctx[t * 8 + 2 * i]     = __uint_as_float(ww[i] << 16);
                s_ctx[t * 8 + 2 * i + 1] = __uint_as_float(ww[i] & 0xFFFF0000u);
            }
        }
    } else {
        if (t < 128)
            ((float4*)s_ctx)[t] = ((const float4*)((const float*)ctxv + (size_t)b * D_DIM))[t];
    }
    __syncthreads();

    // ctx norm (scale-invariant rescan margin)
    float cs = s_ctx[t] * s_ctx[t] + s_ctx[t + 256] * s_ctx[t + 256];
    #pragma unroll
    for (int o = 32; o; o >>= 1) cs += __shfl_xor(cs, o, 64);
    if (lane == 0) s_cn[w] = cs;

    // scan this b's group keys (coalesced), find block max.
    const uint32_t* tk = tmax + (size_t)b * ngrp;
    const int nk = ngrp >> 8;          // 16 (fine) or 2 (coarse)
    uint32_t km = 0;
    for (int i = 0; i < nk; ++i) {
        uint32_t v = tk[t + (i << 8)];
        km = v > km ? v : km;
    }
    #pragma unroll
    for (int o = 32; o; o >>= 1) { uint32_t ot = __shfl_xor(km, o, 64); km = ot > km ? ot : km; }
    if (lane == 0) s_red[w] = km;
    __syncthreads();
    uint32_t kbest = s_red[0];
    #pragma unroll
    for (int i = 1; i < 4; ++i) kbest = s_red[i] > kbest ? s_red[i] : kbest;
    const float cnorm = sqrtf(s_cn[0] + s_cn[1] + s_cn[2] + s_cn[3]);
    const uint32_t keyT = f32_order(f32_unorder(kbest) - DELTA_COS * cnorm);

    for (int i = 0; i < nk; ++i) {
        uint32_t v = tk[t + (i << 8)];
        if (v >= keyT) {
            int idx = atomicAdd(&s_cnt, 1);
            if (idx < LISTCAP) s_list[idx] = t + (i << 8);
        }
    }
    __syncthreads();
    int cnt = s_cnt; if (cnt > LISTCAP) cnt = LISTCAP;
    const int total = cnt << gshift;

    // best = (dot, nsq, m); compare via signed-square cross-multiplication
    double bd = -1.0e300, bn = 1.0;
    double bp = bd * 1.0e300;   // -inf
    int bm = 0x7FFFFFFF;
    const float* cb = s_ctx + lane * 8;

    for (int base = w * 2; base < total; base += 8) {
        const bool has1 = (base + 1 < total);
        const int ia = base, ib = has1 ? base + 1 : base;
        const int ma = (s_list[ia >> gshift] << gshift) + (ia & gmask);
        const int mb = (s_list[ib >> gshift] << gshift) + (ib & gmask);
        double d0 = 0.0, n0 = 0.0, d1 = 0.0, n1 = 0.0;
        if (isbf) {
            uint4 va = *((const uint4*)((const uint16_t*)memv + (size_t)ma * D_DIM) + lane);
            uint4 vb = *((const uint4*)((const uint16_t*)memv + (size_t)mb * D_DIM) + lane);
            uint32_t wa[4] = {va.x, va.y, va.z, va.w};
            uint32_t wbv[4] = {vb.x, vb.y, vb.z, vb.w};
            #pragma unroll
            for (int i = 0; i < 4; ++i) {
                float a0 = __uint_as_float(wa[i] << 16);
                float a1 = __uint_as_float(wa[i] & 0xFFFF0000u);
                d0 += (double)a0 * (double)cb[2 * i];
                d0 += (double)a1 * (double)cb[2 * i + 1];
                n0 += (double)a0 * (double)a0 + (double)a1 * (double)a1;
                float b0v = __uint_as_float(wbv[i] << 16);
                float b1v = __uint_as_float(wbv[i] & 0xFFFF0000u);
                d1 += (double)b0v * (double)cb[2 * i];
                d1 += (double)b1v * (double)cb[2 * i + 1];
                n1 += (double)b0v * (double)b0v + (double)b1v * (double)b1v;
            }
        } else {
            const float4* pa = (const float4*)((const float*)memv + (size_t)ma * D_DIM) + lane * 2;
            const float4* pb = (const float4*)((const float*)memv + (size_t)mb * D_DIM) + lane * 2;
            float4 a0 = pa[0], a1 = pa[1], b0v = pb[0], b1v = pb[1];
            float xa[8] = {a0.x, a0.y, a0.z, a0.w, a1.x, a1.y, a1.z, a1.w};
            float xb[8] = {b0v.x, b0v.y, b0v.z, b0v.w, b1v.x, b1v.y, b1v.z, b1v.w};
            #pragma unroll
            for (int i = 0; i < 8; ++i) {
                d0 += (double)xa[i] * (double)cb[i];
                n0 += (double)xa[i] * (double)xa[i];
                d1 += (double)xb[i] * (double)cb[i];
                n1 += (double)xb[i] * (double)xb[i];
            }
        }
        #pragma unroll
        for (int o = 32; o; o >>= 1) {
            d0 += __shfl_xor(d0, o, 64);
            n0 += __shfl_xor(n0, o, 64);
            d1 += __shfl_xor(d1, o, 64);
            n1 += __shfl_xor(n1, o, 64);
        }
        double p0 = d0 * fabs(d0);
        double lhs = p0 * bn, rhs = bp * n0;
        if (lhs > rhs || (lhs == rhs && ma < bm)) { bd = d0; bn = n0; bp = p0; bm = ma; }
        if (has1) {
            double p1 = d1 * fabs(d1);
            double lhs1 = p1 * bn, rhs1 = bp * n1;
            if (lhs1 > rhs1 || (lhs1 == rhs1 && mb < bm)) { bd = d1; bn = n1; bp = p1; bm = mb; }
        }
    }
    if (lane == 0) { s_d[w] = bd; s_n[w] = bn; s_m[w] = bm; }
    __syncthreads();
    if (t == 0) {
        double cd = s_d[0], cn2 = s_n[0], cp = cd * fabs(cd);
        int cm = s_m[0];
        #pragma unroll
        for (int i = 1; i < 4; ++i) {
            double pd = s_d[i], pn = s_n[i], pp = pd * fabs(pd);
            double lhs = pp * cn2, rhs = cp * pn;
            if (lhs > rhs || (lhs == rhs && s_m[i] < cm)) { cd = pd; cn2 = pn; cp = pp; cm = s_m[i]; }
        }
        s_bestm = cm;
    }
    __syncthreads();
    const int mbest = s_bestm;
    if (isbf) {
        if (t < 64)
            ((uint4*)((uint16_t*)outv + (size_t)b * D_DIM))[t] =
                ((const uint4*)((const uint16_t*)memv + (size_t)mbest * D_DIM))[t];
    } else {
        if (t < 128)
            ((float4*)((float*)outv + (size_t)b * D_DIM))[t] =
                ((const float4*)((const float*)memv + (size_t)mbest * D_DIM))[t];
    }
}

extern "C" void kernel_launch(void* const* d_in, const int* in_sizes, int n_in,
                              void* d_out, int out_size, void* d_ws, size_t ws_size,
                              hipStream_t stream) {
    const void* ctx = d_in[0];
    const void* mem = d_in[1];
    if (in_sizes[0] > in_sizes[1]) { ctx = d_in[1]; mem = d_in[0]; }  // ctx is smaller

    const size_t fineBytes   = (size_t)B_CTX * 4096 * 4;   // 8 MB
    const size_t coarseBytes = (size_t)B_CTX * 512 * 4;    // 1 MB
    const size_t ctxBytes    = (size_t)B_CTX * D_DIM * 2;  // 0.5 MB
    const size_t memBytes    = (size_t)M_MEM * D_DIM * 2;  // 64 MB
    const size_t fastBytes   = fineBytes + 256 + ctxBytes + memBytes;  // ~72.5 MB
    dim3 grid(B_CTX / BB, M_MEM / BM);

    if (ws_size >= fastBytes) {
        // fast path: one-pass convert+normalize, then counted-vmcnt bf16 GEMM
        uint32_t* tmax  = (uint32_t*)d_ws;
        uint32_t* flag  = (uint32_t*)((char*)d_ws + fineBytes);
        uint16_t* ctx_b = (uint16_t*)((char*)d_ws + fineBytes + 256);
        uint16_t* mem_s = (uint16_t*)((char*)d_ws + fineBytes + 256 + ctxBytes);
        detect_init<<<1, 64, 0, stream>>>((const uint32_t*)mem, flag);
        convert_scale<<<CVT_BLOCKS, 256, 0, stream>>>(ctx, mem, flag, mem_s, ctx_b);
        score_mfma<<<grid, 256, 0, stream>>>(mem_s, ctx_b, tmax, 0);
        phase2<<<B_CTX, 256, 0, stream>>>(ctx, mem, flag, tmax, d_out, 4096, 4);
    } else if (ws_size >= fineBytes + 256) {
        uint32_t* tmax = (uint32_t*)d_ws;
        uint32_t* flag = (uint32_t*)((char*)d_ws + fineBytes);
        detect_init<<<1, 64, 0, stream>>>((const uint32_t*)mem, flag);
        score_phase1<<<grid, 256, 0, stream>>>(ctx, mem, flag, tmax, 0);
        phase2<<<B_CTX, 256, 0, stream>>>(ctx, mem, flag, tmax, d_out, 4096, 4);
    } else {
        uint32_t* tmax = (uint32_t*)d_ws;
        uint32_t* flag = (uint32_t*)((char*)d_ws + coarseBytes);
        detect_init<<<1, 64, 0, stream>>>((const uint32_t*)mem, flag);
        score_phase1<<<grid, 256, 0, stream>>>(ctx, mem, flag, tmax, 1);
        phase2<<<B_CTX, 256, 0, stream>>>(ctx, mem, flag, tmax, d_out, 512, 7);
    }
}

// Round 6
// 270.550 us; speedup vs baseline: 1.0076x; 1.0076x over previous
//
#include <hip/hip_runtime.h>
#include <hip/hip_bf16.h>
#include <stdint.h>

#define D_DIM 512
#define B_CTX 512
#define M_MEM 65536
#define BM 128
#define BB 128               // legacy fallback tile
#define BBW 256              // fast-path ctx tile (512-thread blocks)
#define BK 32
#define GBK 32               // K-step of the fast bf16 GEMM
#define NIT (D_DIM / GBK)    // 16 K-steps
#define LDSPAD 40            // 80 B row pitch for legacy fallback kernel
#define DELTA_COS 2.5e-3f    // ~35 sigma of bf16 cosine noise, scale-invariant
#define LISTCAP 2048
#define CVT_MEM_BLOCKS (M_MEM / 32)            // 2048: 4 waves x 8 rows each
#define CVT_BLOCKS (CVT_MEM_BLOCKS + B_CTX / 32)

typedef __attribute__((ext_vector_type(8))) short short8;   // 8 bf16 (4 VGPR)
typedef __attribute__((ext_vector_type(4))) float floatx4;  // MFMA accumulator

__device__ __forceinline__ uint32_t f32_order(float s) {    // monotone f32->u32
    uint32_t u = __float_as_uint(s);
    return (u & 0x80000000u) ? ~u : (u | 0x80000000u);
}
__device__ __forceinline__ float f32_unorder(uint32_t v) {
    uint32_t u = (v & 0x80000000u) ? (v & 0x7FFFFFFFu) : ~v;
    return __uint_as_float(u);
}
__device__ __forceinline__ uint32_t pack_bf16_rtn(float a, float b) {
    uint32_t ua = __float_as_uint(a) + 0x8000u;
    uint32_t ub = __float_as_uint(b) + 0x8000u;
    return (ua >> 16) | (ub & 0xFFFF0000u);
}

// async global->LDS, 16B per lane. LDS dest is WAVE-UNIFORM base; HW adds lane*16.
typedef const __attribute__((address_space(1))) void gv_t;
typedef __attribute__((address_space(3))) void lv_t;
__device__ __forceinline__ void gload_lds16(const uint16_t* g, uint16_t* l) {
    __builtin_amdgcn_global_load_lds((gv_t*)g, (lv_t*)l, 16, 0, 0);
}

// ---------------- kernel 0: dtype probe ----------------
__global__ void detect_init(const uint32_t* __restrict__ mem_raw,
                            uint32_t* __restrict__ flag) {
    __shared__ int cnt;
    if (threadIdx.x == 0) cnt = 0;
    __syncthreads();
    int s = 0;
    #pragma unroll
    for (int i = 0; i < 8; ++i) {
        uint32_t u = mem_raw[threadIdx.x * 8 + i];
        uint32_t e = (u >> 7) & 0xFFu;   // exponent of LOW bf16 half
        s += (e >= 96u && e <= 144u) ? 1 : 0;
    }
    atomicAdd(&cnt, s);
    __syncthreads();
    if (threadIdx.x == 0) *flag = (cnt > 256) ? 1u : 0u;   // 1 == bf16 inputs
}

// ---- kernel A: one-pass convert. mem -> bf16(mem * 1/|mem|), ctx -> bf16(ctx) ----
__global__ __launch_bounds__(256) void convert_scale(const void* __restrict__ ctxv,
                                                     const void* __restrict__ memv,
                                                     const uint32_t* __restrict__ flag,
                                                     uint16_t* __restrict__ mem_s,
                                                     uint16_t* __restrict__ ctx_b) {
    const bool isbf = (*flag != 0u);
    const int lane = threadIdx.x & 63;
    const int w = threadIdx.x >> 6;
    if (blockIdx.x < CVT_MEM_BLOCKS) {
        const int gw = blockIdx.x * 4 + w;           // 0..8191
        #pragma unroll
        for (int i = 0; i < 8; ++i) {
            const int r = gw * 8 + i;                // 0..65535
            float x[8];
            if (isbf) {
                uint4 v = *((const uint4*)((const uint16_t*)memv + (size_t)r * D_DIM) + lane);
                uint32_t ww[4] = {v.x, v.y, v.z, v.w};
                #pragma unroll
                for (int j = 0; j < 4; ++j) {
                    x[2 * j]     = __uint_as_float(ww[j] << 16);
                    x[2 * j + 1] = __uint_as_float(ww[j] & 0xFFFF0000u);
                }
            } else {
                const float4* p = (const float4*)((const float*)memv + (size_t)r * D_DIM) + lane * 2;
                float4 a = p[0], bq = p[1];
                x[0] = a.x; x[1] = a.y; x[2] = a.z; x[3] = a.w;
                x[4] = bq.x; x[5] = bq.y; x[6] = bq.z; x[7] = bq.w;
            }
            float nsq = 0.f;
            #pragma unroll
            for (int j = 0; j < 8; ++j) nsq = fmaf(x[j], x[j], nsq);
            #pragma unroll
            for (int o = 32; o; o >>= 1) nsq += __shfl_xor(nsq, o, 64);
            const float invn = rsqrtf(fmaxf(nsq, 1e-12f));
            uint4 ov;
            ov.x = pack_bf16_rtn(x[0] * invn, x[1] * invn);
            ov.y = pack_bf16_rtn(x[2] * invn, x[3] * invn);
            ov.z = pack_bf16_rtn(x[4] * invn, x[5] * invn);
            ov.w = pack_bf16_rtn(x[6] * invn, x[7] * invn);
            *((uint4*)(mem_s + (size_t)r * D_DIM) + lane) = ov;
        }
    } else {
        const int gw = (blockIdx.x - CVT_MEM_BLOCKS) * 4 + w;   // 0..63
        #pragma unroll
        for (int i = 0; i < 8; ++i) {
            const int r = gw * 8 + i;                // 0..511
            uint4 ov;
            if (isbf) {
                ov = *((const uint4*)((const uint16_t*)ctxv + (size_t)r * D_DIM) + lane);
            } else {
                const float4* p = (const float4*)((const float*)ctxv + (size_t)r * D_DIM) + lane * 2;
                float4 a = p[0], bq = p[1];
                ov.x = pack_bf16_rtn(a.x, a.y);
                ov.y = pack_bf16_rtn(a.z, a.w);
                ov.z = pack_bf16_rtn(bq.x, bq.y);
                ov.w = pack_bf16_rtn(bq.z, bq.w);
            }
            *((uint4*)(ctx_b + (size_t)r * D_DIM) + lane) = ov;
        }
    }
}

// ---- kernel B: pure-bf16 MFMA GEMM, 512-thread blocks, BM=128 x BBW=256.
// Halves block count vs 128x128: A-panel L3 traffic 256->128 MB, barriers/
// staging-instructions/prologues halve; MFMA+LDS-read totals unchanged.
// Counted-vmcnt dbuf (STAGE=3 gloads/wave -> vmcnt(3)); T2 chunk-XOR swizzle
// (pre-swizzled global source + swizzled ds_read, rule #21); bijective
// XCD-chunked remap. Keys pre-normalized: key = acc directly. ----
#define STAGE2(buf, kofs)                                                          \
    do {                                                                           \
        gload_lds16(ga  + (kofs), &at[buf][0][0] + (size_t)((w << 6)) * 8);        \
        gload_lds16(gb0 + (kofs), &bt[buf][0][0] + (size_t)((w << 6)) * 8);        \
        gload_lds16(gb1 + (kofs), &bt[buf][0][0] + (size_t)(512 + (w << 6)) * 8);  \
    } while (0)

__global__ __launch_bounds__(512, 4) void score_mfma(const uint16_t* __restrict__ A,   // mem_s [M][512]
                                                     const uint16_t* __restrict__ Bc,  // ctx_b [B][512]
                                                     uint32_t* __restrict__ tmax,
                                                     int coarse) {
    __shared__ __align__(16) uint16_t at[2][BM][GBK];    // 2 x 8KB, LINEAR dest
    __shared__ __align__(16) uint16_t bt[2][BBW][GBK];   // 2 x 16KB
    __shared__ uint32_t s_gbest[8][BBW];                 // 8KB

    // bijective XCD-chunked remap: h&7 = XCD (HW round-robin). Each XCD owns a
    // contiguous strip of (m-panel, b-panel) pairs; the 2 blocks sharing an
    // A-panel are consecutive on the same XCD -> A hits that XCD's L2.
    const int h  = blockIdx.y * gridDim.x + blockIdx.x;   // 0..1023
    const int v  = (h & 7) * 128 + (h >> 3);
    const int bxp = v & 1;                                // b-panel 0..1
    const int byp = v >> 1;                               // m-panel 0..511

    const int t    = threadIdx.x;
    const int b0   = bxp * BBW;
    const int m0   = byp * BM;
    const int lane = t & 63;
    const int w    = t >> 6;          // 0..7
    const int wm   = w >> 2;          // 0..1  (64-row half of A tile)
    const int wb   = w & 3;           // 0..3  (64-col quarter of B tile)
    const int quad = lane >> 4;
    const int l15  = lane & 15;
    // T2 swizzle for 64B row pitch: 16B chunk-in-row (0..3) XOR ((row>>1)&3).
    // Staging row = t>>2 (and +128 for B's second half; +128 preserves the XOR
    // since 128 = 0 mod 4 after >>1). Involution with the read-side XOR.
    const int scol_sw = (((t & 3) ^ ((t >> 3) & 3)) << 3);   // staging element col
    const int rc = ((quad ^ ((l15 >> 1) & 3)) << 3);         // read element col

    const uint16_t* ga  = A  + (size_t)(m0 + (t >> 2)) * D_DIM + scol_sw;
    const uint16_t* gb0 = Bc + (size_t)(b0 + (t >> 2)) * D_DIM + scol_sw;
    const uint16_t* gb1 = gb0 + (size_t)128 * D_DIM;

    floatx4 acc[4][4];
    #pragma unroll
    for (int i = 0; i < 4; ++i)
        #pragma unroll
        for (int j = 0; j < 4; ++j)
            acc[i][j] = (floatx4){0.f, 0.f, 0.f, 0.f};

    // prologue: stage tile 0 (3 loads/wave outstanding)
    STAGE2(0, 0);

    #pragma unroll
    for (int it = 0; it < NIT; ++it) {
        const int cur = it & 1;
        if (it < NIT - 1) STAGE2(cur ^ 1, (it + 1) * GBK);   // +3 loads, in flight
        // wait ONLY for the current tile (oldest 3); next tile stays in flight.
        if (it < NIT - 1) asm volatile("s_waitcnt vmcnt(3)" ::: "memory");
        else              asm volatile("s_waitcnt vmcnt(0)" ::: "memory");
        __builtin_amdgcn_sched_barrier(0);
        __builtin_amdgcn_s_barrier();
        __builtin_amdgcn_sched_barrier(0);

        short8 af[4], bg[4];
        #pragma unroll
        for (int i = 0; i < 4; ++i)
            af[i] = *(const short8*)&at[cur][wm * 64 + i * 16 + l15][rc];
        #pragma unroll
        for (int j = 0; j < 4; ++j)
            bg[j] = *(const short8*)&bt[cur][wb * 64 + j * 16 + l15][rc];
        #pragma unroll
        for (int i = 0; i < 4; ++i)
            #pragma unroll
            for (int j = 0; j < 4; ++j)
                acc[i][j] = __builtin_amdgcn_mfma_f32_16x16x32_bf16(af[i], bg[j], acc[i][j], 0, 0, 0);

        if (it < NIT - 1) {
            // trailing barrier: buf[cur] is re-staged next iteration. Drain
            // ds_reads (lgkmcnt) but NOT vmcnt (prefetch stays in flight).
            __builtin_amdgcn_sched_barrier(0);
            asm volatile("s_waitcnt lgkmcnt(0)" ::: "memory");
            __builtin_amdgcn_s_barrier();
            __builtin_amdgcn_sched_barrier(0);
        }
    }

    // group epilogue: frag i == 16-row group (wm*4+i). Cross-quad shuffle, no atomics.
    #pragma unroll
    for (int i = 0; i < 4; ++i)
        #pragma unroll
        for (int j = 0; j < 4; ++j) {
            uint32_t k = 0;
            #pragma unroll
            for (int r = 0; r < 4; ++r) {
                uint32_t kk = f32_order(acc[i][j][r]);   // already cos * |ctx|
                k = kk > k ? kk : k;
            }
            uint32_t o1 = __shfl_xor(k, 16, 64); k = o1 > k ? o1 : k;
            uint32_t o2 = __shfl_xor(k, 32, 64); k = o2 > k ? o2 : k;
            if (quad == 0) s_gbest[wm * 4 + i][wb * 64 + j * 16 + l15] = k;
        }
    __syncthreads();

    if (!coarse) {
        const int G0 = byp * 8;
        for (int e = t; e < 8 * BBW; e += 512) {
            const int col = e >> 3, g = e & 7;
            tmax[(size_t)(b0 + col) * 4096 + G0 + g] = s_gbest[g][col];
        }
    } else {
        if (t < BBW) {
            uint32_t k = s_gbest[0][t];
            #pragma unroll
            for (int g = 1; g < 8; ++g) k = s_gbest[g][t] > k ? s_gbest[g][t] : k;
            tmax[(size_t)(b0 + t) * 512 + byp] = k;
        }
    }
}

// ---- legacy kernel 1 (fallback when workspace too small for bf16 copies) ----
__global__ __launch_bounds__(256) void score_phase1(const void* __restrict__ ctxv,
                                                    const void* __restrict__ memv,
                                                    const uint32_t* __restrict__ flag,
                                                    uint32_t* __restrict__ tmax,
                                                    int coarse) {
    __shared__ __align__(16) uint16_t at[BM][LDSPAD];
    __shared__ __align__(16) uint16_t bt[BB][LDSPAD];
    __shared__ float s_nsq[BM];
    __shared__ uint32_t s_gbest[8][BB];

    const int t    = threadIdx.x;
    const int b0   = blockIdx.x * BB;
    const int m0   = blockIdx.y * BM;
    const int lane = t & 63;
    const int w    = t >> 6;
    const int wm   = w >> 1;
    const int wb   = w & 1;
    const int quad = lane >> 4;
    const int l15  = lane & 15;
    const int srow = t >> 2;
    const int scol = (t & 3) * 8;

    floatx4 acc[4][4];
    #pragma unroll
    for (int i = 0; i < 4; ++i)
        #pragma unroll
        for (int j = 0; j < 4; ++j)
            acc[i][j] = (floatx4){0.f, 0.f, 0.f, 0.f};

    float nsq0 = 0.f, nsq1 = 0.f;
    const bool isbf = (*flag != 0u);

    for (int k0 = 0; k0 < D_DIM; k0 += BK) {
        __syncthreads();
        if (isbf) {
            const uint16_t* mp = (const uint16_t*)memv;
            const uint16_t* cp = (const uint16_t*)ctxv;
            uint4 va0 = *(const uint4*)(mp + (size_t)(m0 + srow) * D_DIM + k0 + scol);
            uint4 va1 = *(const uint4*)(mp + (size_t)(m0 + srow + 64) * D_DIM + k0 + scol);
            uint4 vb0 = *(const uint4*)(cp + (size_t)(b0 + srow) * D_DIM + k0 + scol);
            uint4 vb1 = *(const uint4*)(cp + (size_t)(b0 + srow + 64) * D_DIM + k0 + scol);
            *(uint4*)&at[srow][scol] = va0;
            *(uint4*)&at[srow + 64][scol] = va1;
            *(uint4*)&bt[srow][scol] = vb0;
            *(uint4*)&bt[srow + 64][scol] = vb1;
            uint32_t wa0[4] = {va0.x, va0.y, va0.z, va0.w};
            uint32_t wa1[4] = {va1.x, va1.y, va1.z, va1.w};
            #pragma unroll
            for (int i = 0; i < 4; ++i) {
                float a = __uint_as_float(wa0[i] << 16);
                float b = __uint_as_float(wa0[i] & 0xFFFF0000u);
                nsq0 = fmaf(a, a, nsq0); nsq0 = fmaf(b, b, nsq0);
                float c = __uint_as_float(wa1[i] << 16);
                float d = __uint_as_float(wa1[i] & 0xFFFF0000u);
                nsq1 = fmaf(c, c, nsq1); nsq1 = fmaf(d, d, nsq1);
            }
        } else {
            const float* mp = (const float*)memv;
            const float* cp = (const float*)ctxv;
            const float4* pa0 = (const float4*)(mp + (size_t)(m0 + srow) * D_DIM + k0 + scol);
            const float4* pa1 = (const float4*)(mp + (size_t)(m0 + srow + 64) * D_DIM + k0 + scol);
            const float4* pb0 = (const float4*)(cp + (size_t)(b0 + srow) * D_DIM + k0 + scol);
            const float4* pb1 = (const float4*)(cp + (size_t)(b0 + srow + 64) * D_DIM + k0 + scol);
            float4 a0 = pa0[0], a1 = pa0[1], a2 = pa1[0], a3 = pa1[1];
            float4 c0 = pb0[0], c1 = pb0[1], c2 = pb1[0], c3 = pb1[1];
            uint4 va0 = {pack_bf16_rtn(a0.x, a0.y), pack_bf16_rtn(a0.z, a0.w),
                         pack_bf16_rtn(a1.x, a1.y), pack_bf16_rtn(a1.z, a1.w)};
            uint4 va1 = {pack_bf16_rtn(a2.x, a2.y), pack_bf16_rtn(a2.z, a2.w),
                         pack_bf16_rtn(a3.x, a3.y), pack_bf16_rtn(a3.z, a3.w)};
            uint4 vb0 = {pack_bf16_rtn(c0.x, c0.y), pack_bf16_rtn(c0.z, c0.w),
                         pack_bf16_rtn(c1.x, c1.y), pack_bf16_rtn(c1.z, c1.w)};
            uint4 vb1 = {pack_bf16_rtn(c2.x, c2.y), pack_bf16_rtn(c2.z, c2.w),
                         pack_bf16_rtn(c3.x, c3.y), pack_bf16_rtn(c3.z, c3.w)};
            *(uint4*)&at[srow][scol] = va0;
            *(uint4*)&at[srow + 64][scol] = va1;
            *(uint4*)&bt[srow][scol] = vb0;
            *(uint4*)&bt[srow + 64][scol] = vb1;
            nsq0 = fmaf(a0.x, a0.x, nsq0); nsq0 = fmaf(a0.y, a0.y, nsq0);
            nsq0 = fmaf(a0.z, a0.z, nsq0); nsq0 = fmaf(a0.w, a0.w, nsq0);
            nsq0 = fmaf(a1.x, a1.x, nsq0); nsq0 = fmaf(a1.y, a1.y, nsq0);
            nsq0 = fmaf(a1.z, a1.z, nsq0); nsq0 = fmaf(a1.w, a1.w, nsq0);
            nsq1 = fmaf(a2.x, a2.x, nsq1); nsq1 = fmaf(a2.y, a2.y, nsq1);
            nsq1 = fmaf(a2.z, a2.z, nsq1); nsq1 = fmaf(a2.w, a2.w, nsq1);
            nsq1 = fmaf(a3.x, a3.x, nsq1); nsq1 = fmaf(a3.y, a3.y, nsq1);
            nsq1 = fmaf(a3.z, a3.z, nsq1); nsq1 = fmaf(a3.w, a3.w, nsq1);
        }
        __syncthreads();

        short8 af[4], bg[4];
        #pragma unroll
        for (int i = 0; i < 4; ++i)
            af[i] = *(const short8*)&at[wm * 64 + i * 16 + l15][quad * 8];
        #pragma unroll
        for (int j = 0; j < 4; ++j)
            bg[j] = *(const short8*)&bt[wb * 64 + j * 16 + l15][quad * 8];

        #pragma unroll
        for (int i = 0; i < 4; ++i)
            #pragma unroll
            for (int j = 0; j < 4; ++j)
                acc[i][j] = __builtin_amdgcn_mfma_f32_16x16x32_bf16(af[i], bg[j], acc[i][j], 0, 0, 0);
    }

    nsq0 += __shfl_xor(nsq0, 1, 64); nsq0 += __shfl_xor(nsq0, 2, 64);
    nsq1 += __shfl_xor(nsq1, 1, 64); nsq1 += __shfl_xor(nsq1, 2, 64);
    __syncthreads();
    if ((t & 3) == 0) { s_nsq[srow] = nsq0; s_nsq[srow + 64] = nsq1; }
    __syncthreads();

    float invn[4][4];
    #pragma unroll
    for (int i = 0; i < 4; ++i)
        #pragma unroll
        for (int r = 0; r < 4; ++r)
            invn[i][r] = rsqrtf(fmaxf(s_nsq[wm * 64 + i * 16 + quad * 4 + r], 1e-12f));

    #pragma unroll
    for (int i = 0; i < 4; ++i)
        #pragma unroll
        for (int j = 0; j < 4; ++j) {
            uint32_t k = 0;
            #pragma unroll
            for (int r = 0; r < 4; ++r) {
                uint32_t kk = f32_order(acc[i][j][r] * invn[i][r]);
                k = kk > k ? kk : k;
            }
            uint32_t o1 = __shfl_xor(k, 16, 64); k = o1 > k ? o1 : k;
            uint32_t o2 = __shfl_xor(k, 32, 64); k = o2 > k ? o2 : k;
            if (quad == 0) s_gbest[wm * 4 + i][wb * 64 + j * 16 + l15] = k;
        }
    __syncthreads();

    if (!coarse) {
        const int G0 = blockIdx.y * 8;
        for (int e = t; e < 8 * BB; e += 256) {
            const int col = e >> 3, g = e & 7;
            tmax[(size_t)(b0 + col) * 4096 + G0 + g] = s_gbest[g][col];
        }
    } else {
        if (t < BB) {
            uint32_t k = s_gbest[0][t];
            #pragma unroll
            for (int g = 1; g < 8; ++g) k = s_gbest[g][t] > k ? s_gbest[g][t] : k;
            tmax[(size_t)(b0 + t) * 512 + blockIdx.y] = k;
        }
    }
}

// ---------------- kernel 2: exact fp64 rescore of candidate groups + gather ----------------
__global__ __launch_bounds__(256) void phase2(const void* __restrict__ ctxv,
                                              const void* __restrict__ memv,
                                              const uint32_t* __restrict__ flag,
                                              const uint32_t* __restrict__ tmax,
                                              void* __restrict__ outv,
                                              int ngrp, int gshift) {
    __shared__ float s_ctx[D_DIM];
    __shared__ int s_list[LISTCAP];
    __shared__ int s_cnt;
    __shared__ uint32_t s_red[4];
    __shared__ float s_cn[4];
    __shared__ double s_d[4], s_n[4];
    __shared__ int s_m[4];
    __shared__ int s_bestm;

    const int b = blockIdx.x;
    const int t = threadIdx.x;
    const int lane = t & 63;
    const int w = t >> 6;
    const bool isbf = (*flag != 0u);
    const int gmask = (1 << gshift) - 1;

    if (t == 0) s_cnt = 0;
    if (isbf) {
        if (t < 64) {
            uint4 v = *((const uint4*)((const uint16_t*)ctxv + (size_t)b * D_DIM) + t);
            uint32_t ww[4] = {v.x, v.y, v.z, v.w};
            #pragma unroll
            for (int i = 0; i < 4; ++i) {
                s_ctx[t * 8 + 2 * i]     = __uint_as_float(ww[i] << 16);
                s_ctx[t * 8 + 2 * i + 1] = __uint_as_float(ww[i] & 0xFFFF0000u);
            }
        }
    } else {
        if (t < 128)
            ((float4*)s_ctx)[t] = ((const float4*)((const float*)ctxv + (size_t)b * D_DIM))[t];
    }
    __syncthreads();

    // ctx norm (scale-invariant rescan margin)
    float cs = s_ctx[t] * s_ctx[t] + s_ctx[t + 256] * s_ctx[t + 256];
    #pragma unroll
    for (int o = 32; o; o >>= 1) cs += __shfl_xor(cs, o, 64);
    if (lane == 0) s_cn[w] = cs;

    // scan this b's group keys (coalesced), find block max.
    const uint32_t* tk = tmax + (size_t)b * ngrp;
    const int nk = ngrp >> 8;          // 16 (fine) or 2 (coarse)
    uint32_t km = 0;
    for (int i = 0; i < nk; ++i) {
        uint32_t v = tk[t + (i << 8)];
        km = v > km ? v : km;
    }
    #pragma unroll
    for (int o = 32; o; o >>= 1) { uint32_t ot = __shfl_xor(km, o, 64); km = ot > km ? ot : km; }
    if (lane == 0) s_red[w] = km;
    __syncthreads();
    uint32_t kbest = s_red[0];
    #pragma unroll
    for (int i = 1; i < 4; ++i) kbest = s_red[i] > kbest ? s_red[i] : kbest;
    const float cnorm = sqrtf(s_cn[0] + s_cn[1] + s_cn[2] + s_cn[3]);
    const uint32_t keyT = f32_order(f32_unorder(kbest) - DELTA_COS * cnorm);

    for (int i = 0; i < nk; ++i) {
        uint32_t v = tk[t + (i << 8)];
        if (v >= keyT) {
            int idx = atomicAdd(&s_cnt, 1);
            if (idx < LISTCAP) s_list[idx] = t + (i << 8);
        }
    }
    __syncthreads();
    int cnt = s_cnt; if (cnt > LISTCAP) cnt = LISTCAP;
    const int total = cnt << gshift;

    // best = (dot, nsq, m); compare via signed-square cross-multiplication
    double bd = -1.0e300, bn = 1.0;
    double bp = bd * 1.0e300;   // -inf
    int bm = 0x7FFFFFFF;
    const float* cb = s_ctx + lane * 8;

    for (int base = w * 2; base < total; base += 8) {
        const bool has1 = (base + 1 < total);
        const int ia = base, ib = has1 ? base + 1 : base;
        const int ma = (s_list[ia >> gshift] << gshift) + (ia & gmask);
        const int mb = (s_list[ib >> gshift] << gshift) + (ib & gmask);
        double d0 = 0.0, n0 = 0.0, d1 = 0.0, n1 = 0.0;
        if (isbf) {
            uint4 va = *((const uint4*)((const uint16_t*)memv + (size_t)ma * D_DIM) + lane);
            uint4 vb = *((const uint4*)((const uint16_t*)memv + (size_t)mb * D_DIM) + lane);
            uint32_t wa[4] = {va.x, va.y, va.z, va.w};
            uint32_t wbv[4] = {vb.x, vb.y, vb.z, vb.w};
            #pragma unroll
            for (int i = 0; i < 4; ++i) {
                float a0 = __uint_as_float(wa[i] << 16);
                float a1 = __uint_as_float(wa[i] & 0xFFFF0000u);
                d0 += (double)a0 * (double)cb[2 * i];
                d0 += (double)a1 * (double)cb[2 * i + 1];
                n0 += (double)a0 * (double)a0 + (double)a1 * (double)a1;
                float b0v = __uint_as_float(wbv[i] << 16);
                float b1v = __uint_as_float(wbv[i] & 0xFFFF0000u);
                d1 += (double)b0v * (double)cb[2 * i];
                d1 += (double)b1v * (double)cb[2 * i + 1];
                n1 += (double)b0v * (double)b0v + (double)b1v * (double)b1v;
            }
        } else {
            const float4* pa = (const float4*)((const float*)memv + (size_t)ma * D_DIM) + lane * 2;
            const float4* pb = (const float4*)((const float*)memv + (size_t)mb * D_DIM) + lane * 2;
            float4 a0 = pa[0], a1 = pa[1], b0v = pb[0], b1v = pb[1];
            float xa[8] = {a0.x, a0.y, a0.z, a0.w, a1.x, a1.y, a1.z, a1.w};
            float xb[8] = {b0v.x, b0v.y, b0v.z, b0v.w, b1v.x, b1v.y, b1v.z, b1v.w};
            #pragma unroll
            for (int i = 0; i < 8; ++i) {
                d0 += (double)xa[i] * (double)cb[i];
                n0 += (double)xa[i] * (double)xa[i];
                d1 += (double)xb[i] * (double)cb[i];
                n1 += (double)xb[i] * (double)xb[i];
            }
        }
        #pragma unroll
        for (int o = 32; o; o >>= 1) {
            d0 += __shfl_xor(d0, o, 64);
            n0 += __shfl_xor(n0, o, 64);
            d1 += __shfl_xor(d1, o, 64);
            n1 += __shfl_xor(n1, o, 64);
        }
        double p0 = d0 * fabs(d0);
        double lhs = p0 * bn, rhs = bp * n0;
        if (lhs > rhs || (lhs == rhs && ma < bm)) { bd = d0; bn = n0; bp = p0; bm = ma; }
        if (has1) {
            double p1 = d1 * fabs(d1);
            double lhs1 = p1 * bn, rhs1 = bp * n1;
            if (lhs1 > rhs1 || (lhs1 == rhs1 && mb < bm)) { bd = d1; bn = n1; bp = p1; bm = mb; }
        }
    }
    if (lane == 0) { s_d[w] = bd; s_n[w] = bn; s_m[w] = bm; }
    __syncthreads();
    if (t == 0) {
        double cd = s_d[0], cn2 = s_n[0], cp = cd * fabs(cd);
        int cm = s_m[0];
        #pragma unroll
        for (int i = 1; i < 4; ++i) {
            double pd = s_d[i], pn = s_n[i], pp = pd * fabs(pd);
            double lhs = pp * cn2, rhs = cp * pn;
            if (lhs > rhs || (lhs == rhs && s_m[i] < cm)) { cd = pd; cn2 = pn; cp = pp; cm = s_m[i]; }
        }
        s_bestm = cm;
    }
    __syncthreads();
    const int mbest = s_bestm;
    if (isbf) {
        if (t < 64)
            ((uint4*)((uint16_t*)outv + (size_t)b * D_DIM))[t] =
                ((const uint4*)((const uint16_t*)memv + (size_t)mbest * D_DIM))[t];
    } else {
        if (t < 128)
            ((float4*)((float*)outv + (size_t)b * D_DIM))[t] =
                ((const float4*)((const float*)memv + (size_t)mbest * D_DIM))[t];
    }
}

extern "C" void kernel_launch(void* const* d_in, const int* in_sizes, int n_in,
                              void* d_out, int out_size, void* d_ws, size_t ws_size,
                              hipStream_t stream) {
    const void* ctx = d_in[0];
    const void* mem = d_in[1];
    if (in_sizes[0] > in_sizes[1]) { ctx = d_in[1]; mem = d_in[0]; }  // ctx is smaller

    const size_t fineBytes   = (size_t)B_CTX * 4096 * 4;   // 8 MB
    const size_t coarseBytes = (size_t)B_CTX * 512 * 4;    // 1 MB
    const size_t ctxBytes    = (size_t)B_CTX * D_DIM * 2;  // 0.5 MB
    const size_t memBytes    = (size_t)M_MEM * D_DIM * 2;  // 64 MB
    const size_t fastBytes   = fineBytes + 256 + ctxBytes + memBytes;  // ~72.5 MB

    if (ws_size >= fastBytes) {
        // fast path: one-pass convert+normalize, then 512-thread counted-vmcnt GEMM
        uint32_t* tmax  = (uint32_t*)d_ws;
        uint32_t* flag  = (uint32_t*)((char*)d_ws + fineBytes);
        uint16_t* ctx_b = (uint16_t*)((char*)d_ws + fineBytes + 256);
        uint16_t* mem_s = (uint16_t*)((char*)d_ws + fineBytes + 256 + ctxBytes);
        dim3 grid(B_CTX / BBW, M_MEM / BM);    // (2, 512)
        detect_init<<<1, 64, 0, stream>>>((const uint32_t*)mem, flag);
        convert_scale<<<CVT_BLOCKS, 256, 0, stream>>>(ctx, mem, flag, mem_s, ctx_b);
        score_mfma<<<grid, 512, 0, stream>>>(mem_s, ctx_b, tmax, 0);
        phase2<<<B_CTX, 256, 0, stream>>>(ctx, mem, flag, tmax, d_out, 4096, 4);
    } else if (ws_size >= fineBytes + 256) {
        uint32_t* tmax = (uint32_t*)d_ws;
        uint32_t* flag = (uint32_t*)((char*)d_ws + fineBytes);
        dim3 grid(B_CTX / BB, M_MEM / BM);
        detect_init<<<1, 64, 0, stream>>>((const uint32_t*)mem, flag);
        score_phase1<<<grid, 256, 0, stream>>>(ctx, mem, flag, tmax, 0);
        phase2<<<B_CTX, 256, 0, stream>>>(ctx, mem, flag, tmax, d_out, 4096, 4);
    } else {
        uint32_t* tmax = (uint32_t*)d_ws;
        uint32_t* flag = (uint32_t*)((char*)d_ws + coarseBytes);
        dim3 grid(B_CTX / BB, M_MEM / BM);
        detect_init<<<1, 64, 0, stream>>>((const uint32_t*)mem, flag);
        score_phase1<<<grid, 256, 0, stream>>>(ctx, mem, flag, tmax, 1);
        phase2<<<B_CTX, 256, 0, stream>>>(ctx, mem, flag, tmax, d_out, 512, 7);
    }
}

// Round 7
// 266.949 us; speedup vs baseline: 1.0212x; 1.0135x over previous
//
#include <hip/hip_runtime.h>
#include <hip/hip_bf16.h>
#include <stdint.h>

#define D_DIM 512
#define B_CTX 512
#define M_MEM 65536
#define BM 128
#define BB 128               // legacy fallback tile
#define BBW 256              // fast-path ctx tile (512-thread blocks)
#define BK 32
#define GBK 32               // K-step of the fast bf16 GEMM
#define NIT (D_DIM / GBK)    // 16 K-steps
#define LDSPAD 40            // 80 B row pitch for legacy fallback kernel
#define DELTA_COS 2.5e-3f    // ~35 sigma of bf16 cosine noise, scale-invariant
#define LISTCAP 2048
#define CVT_MEM_BLOCKS (M_MEM / 32)            // 2048: 4 waves x 8 rows each
#define CVT_BLOCKS (CVT_MEM_BLOCKS + B_CTX / 32)

typedef __attribute__((ext_vector_type(8))) short short8;   // 8 bf16 (4 VGPR)
typedef __attribute__((ext_vector_type(4))) float floatx4;  // MFMA accumulator

__device__ __forceinline__ uint32_t f32_order(float s) {    // monotone f32->u32
    uint32_t u = __float_as_uint(s);
    return (u & 0x80000000u) ? ~u : (u | 0x80000000u);
}
__device__ __forceinline__ float f32_unorder(uint32_t v) {
    uint32_t u = (v & 0x80000000u) ? (v & 0x7FFFFFFFu) : ~v;
    return __uint_as_float(u);
}
__device__ __forceinline__ uint32_t pack_bf16_rtn(float a, float b) {
    uint32_t ua = __float_as_uint(a) + 0x8000u;
    uint32_t ub = __float_as_uint(b) + 0x8000u;
    return (ua >> 16) | (ub & 0xFFFF0000u);
}

// async global->LDS, 16B per lane. LDS dest is WAVE-UNIFORM base; HW adds lane*16.
typedef const __attribute__((address_space(1))) void gv_t;
typedef __attribute__((address_space(3))) void lv_t;
__device__ __forceinline__ void gload_lds16(const uint16_t* g, uint16_t* l) {
    __builtin_amdgcn_global_load_lds((gv_t*)g, (lv_t*)l, 16, 0, 0);
}

// ---------------- kernel 0: dtype probe ----------------
__global__ void detect_init(const uint32_t* __restrict__ mem_raw,
                            uint32_t* __restrict__ flag) {
    __shared__ int cnt;
    if (threadIdx.x == 0) cnt = 0;
    __syncthreads();
    int s = 0;
    #pragma unroll
    for (int i = 0; i < 8; ++i) {
        uint32_t u = mem_raw[threadIdx.x * 8 + i];
        uint32_t e = (u >> 7) & 0xFFu;   // exponent of LOW bf16 half
        s += (e >= 96u && e <= 144u) ? 1 : 0;
    }
    atomicAdd(&cnt, s);
    __syncthreads();
    if (threadIdx.x == 0) *flag = (cnt > 256) ? 1u : 0u;   // 1 == bf16 inputs
}

// ---- kernel A: one-pass convert. mem -> bf16(mem * 1/|mem|), ctx -> bf16(ctx) ----
__global__ __launch_bounds__(256) void convert_scale(const void* __restrict__ ctxv,
                                                     const void* __restrict__ memv,
                                                     const uint32_t* __restrict__ flag,
                                                     uint16_t* __restrict__ mem_s,
                                                     uint16_t* __restrict__ ctx_b) {
    const bool isbf = (*flag != 0u);
    const int lane = threadIdx.x & 63;
    const int w = threadIdx.x >> 6;
    if (blockIdx.x < CVT_MEM_BLOCKS) {
        const int gw = blockIdx.x * 4 + w;           // 0..8191
        #pragma unroll
        for (int i = 0; i < 8; ++i) {
            const int r = gw * 8 + i;                // 0..65535
            float x[8];
            if (isbf) {
                uint4 v = *((const uint4*)((const uint16_t*)memv + (size_t)r * D_DIM) + lane);
                uint32_t ww[4] = {v.x, v.y, v.z, v.w};
                #pragma unroll
                for (int j = 0; j < 4; ++j) {
                    x[2 * j]     = __uint_as_float(ww[j] << 16);
                    x[2 * j + 1] = __uint_as_float(ww[j] & 0xFFFF0000u);
                }
            } else {
                const float4* p = (const float4*)((const float*)memv + (size_t)r * D_DIM) + lane * 2;
                float4 a = p[0], bq = p[1];
                x[0] = a.x; x[1] = a.y; x[2] = a.z; x[3] = a.w;
                x[4] = bq.x; x[5] = bq.y; x[6] = bq.z; x[7] = bq.w;
            }
            float nsq = 0.f;
            #pragma unroll
            for (int j = 0; j < 8; ++j) nsq = fmaf(x[j], x[j], nsq);
            #pragma unroll
            for (int o = 32; o; o >>= 1) nsq += __shfl_xor(nsq, o, 64);
            const float invn = rsqrtf(fmaxf(nsq, 1e-12f));
            uint4 ov;
            ov.x = pack_bf16_rtn(x[0] * invn, x[1] * invn);
            ov.y = pack_bf16_rtn(x[2] * invn, x[3] * invn);
            ov.z = pack_bf16_rtn(x[4] * invn, x[5] * invn);
            ov.w = pack_bf16_rtn(x[6] * invn, x[7] * invn);
            *((uint4*)(mem_s + (size_t)r * D_DIM) + lane) = ov;
        }
    } else {
        const int gw = (blockIdx.x - CVT_MEM_BLOCKS) * 4 + w;   // 0..63
        #pragma unroll
        for (int i = 0; i < 8; ++i) {
            const int r = gw * 8 + i;                // 0..511
            uint4 ov;
            if (isbf) {
                ov = *((const uint4*)((const uint16_t*)ctxv + (size_t)r * D_DIM) + lane);
            } else {
                const float4* p = (const float4*)((const float*)ctxv + (size_t)r * D_DIM) + lane * 2;
                float4 a = p[0], bq = p[1];
                ov.x = pack_bf16_rtn(a.x, a.y);
                ov.y = pack_bf16_rtn(a.z, a.w);
                ov.z = pack_bf16_rtn(bq.x, bq.y);
                ov.w = pack_bf16_rtn(bq.z, bq.w);
            }
            *((uint4*)(ctx_b + (size_t)r * D_DIM) + lane) = ov;
        }
    }
}

// ---- kernel B: pure-bf16 MFMA GEMM, TRIPLE-buffered, ONE barrier per K-step,
// counted vmcnt (prefetch never drained in the main loop). Staging targets
// buf[(it+1)%3]; slowest wave (bounded by barrier it-1) reads buf[(it-1)%3];
// distance-2 mod 3 never collides -> no trailing barrier, no lgkm drain needed
// (each wave's ds_reads are consumed by its own MFMAs before the next barrier).
// T2 chunk-XOR swizzle (pre-swizzled global src + swizzled ds_read, rule #21);
// bijective XCD-chunked remap; T5 setprio around the MFMA cluster. ----
#define STAGE3(buf, kofs)                                                          \
    do {                                                                           \
        gload_lds16(ga  + (kofs), &at[buf][0][0] + (size_t)((w << 6)) * 8);        \
        gload_lds16(gb0 + (kofs), &bt[buf][0][0] + (size_t)((w << 6)) * 8);        \
        gload_lds16(gb1 + (kofs), &bt[buf][0][0] + (size_t)(512 + (w << 6)) * 8);  \
    } while (0)

__global__ __launch_bounds__(512, 4) void score_mfma(const uint16_t* __restrict__ A,   // mem_s [M][512]
                                                     const uint16_t* __restrict__ Bc,  // ctx_b [B][512]
                                                     uint32_t* __restrict__ tmax,
                                                     int coarse) {
    __shared__ __align__(16) uint16_t at[3][BM][GBK];    // 3 x 8KB, LINEAR dest
    __shared__ __align__(16) uint16_t bt[3][BBW][GBK];   // 3 x 16KB
    __shared__ uint32_t s_gbest[8][BBW];                 // 8KB  -> 80KB total, 2 blocks/CU

    // bijective XCD-chunked remap: h&7 = XCD (HW round-robin). Each XCD owns a
    // contiguous strip of (m-panel, b-panel) pairs; the 2 blocks sharing an
    // A-panel are consecutive on the same XCD -> A hits that XCD's L2.
    const int h  = blockIdx.y * gridDim.x + blockIdx.x;   // 0..1023
    const int v  = (h & 7) * 128 + (h >> 3);
    const int bxp = v & 1;                                // b-panel 0..1
    const int byp = v >> 1;                               // m-panel 0..511

    const int t    = threadIdx.x;
    const int b0   = bxp * BBW;
    const int m0   = byp * BM;
    const int lane = t & 63;
    const int w    = t >> 6;          // 0..7
    const int wm   = w >> 2;          // 0..1  (64-row half of A tile)
    const int wb   = w & 3;           // 0..3  (64-col quarter of B tile)
    const int quad = lane >> 4;
    const int l15  = lane & 15;
    // T2 swizzle for 64B row pitch: 16B chunk-in-row (0..3) XOR ((row>>1)&3).
    // Stage pulls global chunk (r, j^f(r)) into linear LDS chunk (r, j); read
    // applies the same XOR -> involution (rows +128 preserve the XOR mod 4).
    const int scol_sw = (((t & 3) ^ ((t >> 3) & 3)) << 3);   // staging element col
    const int rc = ((quad ^ ((l15 >> 1) & 3)) << 3);         // read element col

    const uint16_t* ga  = A  + (size_t)(m0 + (t >> 2)) * D_DIM + scol_sw;
    const uint16_t* gb0 = Bc + (size_t)(b0 + (t >> 2)) * D_DIM + scol_sw;
    const uint16_t* gb1 = gb0 + (size_t)128 * D_DIM;

    floatx4 acc[4][4];
    #pragma unroll
    for (int i = 0; i < 4; ++i)
        #pragma unroll
        for (int j = 0; j < 4; ++j)
            acc[i][j] = (floatx4){0.f, 0.f, 0.f, 0.f};

    // prologue: stage tile 0 (3 loads/wave outstanding)
    STAGE3(0, 0);

    #pragma unroll
    for (int it = 0; it < NIT; ++it) {
        const int cur = it % 3;                      // compile-time (full unroll)
        if (it < NIT - 1) STAGE3((it + 1) % 3, (it + 1) * GBK);   // +3 loads, in flight
        // wait for OWN tile-it loads (oldest 3); tile it+1 stays in flight.
        if (it < NIT - 1) asm volatile("s_waitcnt vmcnt(3)" ::: "memory");
        else              asm volatile("s_waitcnt vmcnt(0)" ::: "memory");
        __builtin_amdgcn_sched_barrier(0);
        __builtin_amdgcn_s_barrier();                // now ALL waves' tile-it loads done
        __builtin_amdgcn_sched_barrier(0);

        short8 af[4], bg[4];
        #pragma unroll
        for (int i = 0; i < 4; ++i)
            af[i] = *(const short8*)&at[cur][wm * 64 + i * 16 + l15][rc];
        #pragma unroll
        for (int j = 0; j < 4; ++j)
            bg[j] = *(const short8*)&bt[cur][wb * 64 + j * 16 + l15][rc];
        __builtin_amdgcn_s_setprio(1);
        #pragma unroll
        for (int i = 0; i < 4; ++i)
            #pragma unroll
            for (int j = 0; j < 4; ++j)
                acc[i][j] = __builtin_amdgcn_mfma_f32_16x16x32_bf16(af[i], bg[j], acc[i][j], 0, 0, 0);
        __builtin_amdgcn_s_setprio(0);
    }

    // group epilogue: frag i == 16-row group (wm*4+i). Cross-quad shuffle, no atomics.
    #pragma unroll
    for (int i = 0; i < 4; ++i)
        #pragma unroll
        for (int j = 0; j < 4; ++j) {
            uint32_t k = 0;
            #pragma unroll
            for (int r = 0; r < 4; ++r) {
                uint32_t kk = f32_order(acc[i][j][r]);   // already cos * |ctx|
                k = kk > k ? kk : k;
            }
            uint32_t o1 = __shfl_xor(k, 16, 64); k = o1 > k ? o1 : k;
            uint32_t o2 = __shfl_xor(k, 32, 64); k = o2 > k ? o2 : k;
            if (quad == 0) s_gbest[wm * 4 + i][wb * 64 + j * 16 + l15] = k;
        }
    __syncthreads();

    if (!coarse) {
        const int G0 = byp * 8;
        for (int e = t; e < 8 * BBW; e += 512) {
            const int col = e >> 3, g = e & 7;
            tmax[(size_t)(b0 + col) * 4096 + G0 + g] = s_gbest[g][col];
        }
    } else {
        if (t < BBW) {
            uint32_t k = s_gbest[0][t];
            #pragma unroll
            for (int g = 1; g < 8; ++g) k = s_gbest[g][t] > k ? s_gbest[g][t] : k;
            tmax[(size_t)(b0 + t) * 512 + byp] = k;
        }
    }
}

// ---- legacy kernel 1 (fallback when workspace too small for bf16 copies) ----
__global__ __launch_bounds__(256) void score_phase1(const void* __restrict__ ctxv,
                                                    const void* __restrict__ memv,
                                                    const uint32_t* __restrict__ flag,
                                                    uint32_t* __restrict__ tmax,
                                                    int coarse) {
    __shared__ __align__(16) uint16_t at[BM][LDSPAD];
    __shared__ __align__(16) uint16_t bt[BB][LDSPAD];
    __shared__ float s_nsq[BM];
    __shared__ uint32_t s_gbest[8][BB];

    const int t    = threadIdx.x;
    const int b0   = blockIdx.x * BB;
    const int m0   = blockIdx.y * BM;
    const int lane = t & 63;
    const int w    = t >> 6;
    const int wm   = w >> 1;
    const int wb   = w & 1;
    const int quad = lane >> 4;
    const int l15  = lane & 15;
    const int srow = t >> 2;
    const int scol = (t & 3) * 8;

    floatx4 acc[4][4];
    #pragma unroll
    for (int i = 0; i < 4; ++i)
        #pragma unroll
        for (int j = 0; j < 4; ++j)
            acc[i][j] = (floatx4){0.f, 0.f, 0.f, 0.f};

    float nsq0 = 0.f, nsq1 = 0.f;
    const bool isbf = (*flag != 0u);

    for (int k0 = 0; k0 < D_DIM; k0 += BK) {
        __syncthreads();
        if (isbf) {
            const uint16_t* mp = (const uint16_t*)memv;
            const uint16_t* cp = (const uint16_t*)ctxv;
            uint4 va0 = *(const uint4*)(mp + (size_t)(m0 + srow) * D_DIM + k0 + scol);
            uint4 va1 = *(const uint4*)(mp + (size_t)(m0 + srow + 64) * D_DIM + k0 + scol);
            uint4 vb0 = *(const uint4*)(cp + (size_t)(b0 + srow) * D_DIM + k0 + scol);
            uint4 vb1 = *(const uint4*)(cp + (size_t)(b0 + srow + 64) * D_DIM + k0 + scol);
            *(uint4*)&at[srow][scol] = va0;
            *(uint4*)&at[srow + 64][scol] = va1;
            *(uint4*)&bt[srow][scol] = vb0;
            *(uint4*)&bt[srow + 64][scol] = vb1;
            uint32_t wa0[4] = {va0.x, va0.y, va0.z, va0.w};
            uint32_t wa1[4] = {va1.x, va1.y, va1.z, va1.w};
            #pragma unroll
            for (int i = 0; i < 4; ++i) {
                float a = __uint_as_float(wa0[i] << 16);
                float b = __uint_as_float(wa0[i] & 0xFFFF0000u);
                nsq0 = fmaf(a, a, nsq0); nsq0 = fmaf(b, b, nsq0);
                float c = __uint_as_float(wa1[i] << 16);
                float d = __uint_as_float(wa1[i] & 0xFFFF0000u);
                nsq1 = fmaf(c, c, nsq1); nsq1 = fmaf(d, d, nsq1);
            }
        } else {
            const float* mp = (const float*)memv;
            const float* cp = (const float*)ctxv;
            const float4* pa0 = (const float4*)(mp + (size_t)(m0 + srow) * D_DIM + k0 + scol);
            const float4* pa1 = (const float4*)(mp + (size_t)(m0 + srow + 64) * D_DIM + k0 + scol);
            const float4* pb0 = (const float4*)(cp + (size_t)(b0 + srow) * D_DIM + k0 + scol);
            const float4* pb1 = (const float4*)(cp + (size_t)(b0 + srow + 64) * D_DIM + k0 + scol);
            float4 a0 = pa0[0], a1 = pa0[1], a2 = pa1[0], a3 = pa1[1];
            float4 c0 = pb0[0], c1 = pb0[1], c2 = pb1[0], c3 = pb1[1];
            uint4 va0 = {pack_bf16_rtn(a0.x, a0.y), pack_bf16_rtn(a0.z, a0.w),
                         pack_bf16_rtn(a1.x, a1.y), pack_bf16_rtn(a1.z, a1.w)};
            uint4 va1 = {pack_bf16_rtn(a2.x, a2.y), pack_bf16_rtn(a2.z, a2.w),
                         pack_bf16_rtn(a3.x, a3.y), pack_bf16_rtn(a3.z, a3.w)};
            uint4 vb0 = {pack_bf16_rtn(c0.x, c0.y), pack_bf16_rtn(c0.z, c0.w),
                         pack_bf16_rtn(c1.x, c1.y), pack_bf16_rtn(c1.z, c1.w)};
            uint4 vb1 = {pack_bf16_rtn(c2.x, c2.y), pack_bf16_rtn(c2.z, c2.w),
                         pack_bf16_rtn(c3.x, c3.y), pack_bf16_rtn(c3.z, c3.w)};
            *(uint4*)&at[srow][scol] = va0;
            *(uint4*)&at[srow + 64][scol] = va1;
            *(uint4*)&bt[srow][scol] = vb0;
            *(uint4*)&bt[srow + 64][scol] = vb1;
            nsq0 = fmaf(a0.x, a0.x, nsq0); nsq0 = fmaf(a0.y, a0.y, nsq0);
            nsq0 = fmaf(a0.z, a0.z, nsq0); nsq0 = fmaf(a0.w, a0.w, nsq0);
            nsq0 = fmaf(a1.x, a1.x, nsq0); nsq0 = fmaf(a1.y, a1.y, nsq0);
            nsq0 = fmaf(a1.z, a1.z, nsq0); nsq0 = fmaf(a1.w, a1.w, nsq0);
            nsq1 = fmaf(a2.x, a2.x, nsq1); nsq1 = fmaf(a2.y, a2.y, nsq1);
            nsq1 = fmaf(a2.z, a2.z, nsq1); nsq1 = fmaf(a2.w, a2.w, nsq1);
            nsq1 = fmaf(a3.x, a3.x, nsq1); nsq1 = fmaf(a3.y, a3.y, nsq1);
            nsq1 = fmaf(a3.z, a3.z, nsq1); nsq1 = fmaf(a3.w, a3.w, nsq1);
        }
        __syncthreads();

        short8 af[4], bg[4];
        #pragma unroll
        for (int i = 0; i < 4; ++i)
            af[i] = *(const short8*)&at[wm * 64 + i * 16 + l15][quad * 8];
        #pragma unroll
        for (int j = 0; j < 4; ++j)
            bg[j] = *(const short8*)&bt[wb * 64 + j * 16 + l15][quad * 8];

        #pragma unroll
        for (int i = 0; i < 4; ++i)
            #pragma unroll
            for (int j = 0; j < 4; ++j)
                acc[i][j] = __builtin_amdgcn_mfma_f32_16x16x32_bf16(af[i], bg[j], acc[i][j], 0, 0, 0);
    }

    nsq0 += __shfl_xor(nsq0, 1, 64); nsq0 += __shfl_xor(nsq0, 2, 64);
    nsq1 += __shfl_xor(nsq1, 1, 64); nsq1 += __shfl_xor(nsq1, 2, 64);
    __syncthreads();
    if ((t & 3) == 0) { s_nsq[srow] = nsq0; s_nsq[srow + 64] = nsq1; }
    __syncthreads();

    float invn[4][4];
    #pragma unroll
    for (int i = 0; i < 4; ++i)
        #pragma unroll
        for (int r = 0; r < 4; ++r)
            invn[i][r] = rsqrtf(fmaxf(s_nsq[wm * 64 + i * 16 + quad * 4 + r], 1e-12f));

    #pragma unroll
    for (int i = 0; i < 4; ++i)
        #pragma unroll
        for (int j = 0; j < 4; ++j) {
            uint32_t k = 0;
            #pragma unroll
            for (int r = 0; r < 4; ++r) {
                uint32_t kk = f32_order(acc[i][j][r] * invn[i][r]);
                k = kk > k ? kk : k;
            }
            uint32_t o1 = __shfl_xor(k, 16, 64); k = o1 > k ? o1 : k;
            uint32_t o2 = __shfl_xor(k, 32, 64); k = o2 > k ? o2 : k;
            if (quad == 0) s_gbest[wm * 4 + i][wb * 64 + j * 16 + l15] = k;
        }
    __syncthreads();

    if (!coarse) {
        const int G0 = blockIdx.y * 8;
        for (int e = t; e < 8 * BB; e += 256) {
            const int col = e >> 3, g = e & 7;
            tmax[(size_t)(b0 + col) * 4096 + G0 + g] = s_gbest[g][col];
        }
    } else {
        if (t < BB) {
            uint32_t k = s_gbest[0][t];
            #pragma unroll
            for (int g = 1; g < 8; ++g) k = s_gbest[g][t] > k ? s_gbest[g][t] : k;
            tmax[(size_t)(b0 + t) * 512 + blockIdx.y] = k;
        }
    }
}

// ---------------- kernel 2: exact fp64 rescore of candidate groups + gather ----------------
__global__ __launch_bounds__(256) void phase2(const void* __restrict__ ctxv,
                                              const void* __restrict__ memv,
                                              const uint32_t* __restrict__ flag,
                                              const uint32_t* __restrict__ tmax,
                                              void* __restrict__ outv,
                                              int ngrp, int gshift) {
    __shared__ float s_ctx[D_DIM];
    __shared__ int s_list[LISTCAP];
    __shared__ int s_cnt;
    __shared__ uint32_t s_red[4];
    __shared__ float s_cn[4];
    __shared__ double s_d[4], s_n[4];
    __shared__ int s_m[4];
    __shared__ int s_bestm;

    const int b = blockIdx.x;
    const int t = threadIdx.x;
    const int lane = t & 63;
    const int w = t >> 6;
    const bool isbf = (*flag != 0u);
    const int gmask = (1 << gshift) - 1;

    if (t == 0) s_cnt = 0;
    if (isbf) {
        if (t < 64) {
            uint4 v = *((const uint4*)((const uint16_t*)ctxv + (size_t)b * D_DIM) + t);
            uint32_t ww[4] = {v.x, v.y, v.z, v.w};
            #pragma unroll
            for (int i = 0; i < 4; ++i) {
                s_ctx[t * 8 + 2 * i]     = __uint_as_float(ww[i] << 16);
                s_ctx[t * 8 + 2 * i + 1] = __uint_as_float(ww[i] & 0xFFFF0000u);
            }
        }
    } else {
        if (t < 128)
            ((float4*)s_ctx)[t] = ((const float4*)((const float*)ctxv + (size_t)b * D_DIM))[t];
    }
    __syncthreads();

    // ctx norm (scale-invariant rescan margin)
    float cs = s_ctx[t] * s_ctx[t] + s_ctx[t + 256] * s_ctx[t + 256];
    #pragma unroll
    for (int o = 32; o; o >>= 1) cs += __shfl_xor(cs, o, 64);
    if (lane == 0) s_cn[w] = cs;

    // scan this b's group keys (coalesced), find block max.
    const uint32_t* tk = tmax + (size_t)b * ngrp;
    const int nk = ngrp >> 8;          // 16 (fine) or 2 (coarse)
    uint32_t km = 0;
    for (int i = 0; i < nk; ++i) {
        uint32_t v = tk[t + (i << 8)];
        km = v > km ? v : km;
    }
    #pragma unroll
    for (int o = 32; o; o >>= 1) { uint32_t ot = __shfl_xor(km, o, 64); km = ot > km ? ot : km; }
    if (lane == 0) s_red[w] = km;
    __syncthreads();
    uint32_t kbest = s_red[0];
    #pragma unroll
    for (int i = 1; i < 4; ++i) kbest = s_red[i] > kbest ? s_red[i] : kbest;
    const float cnorm = sqrtf(s_cn[0] + s_cn[1] + s_cn[2] + s_cn[3]);
    const uint32_t keyT = f32_order(f32_unorder(kbest) - DELTA_COS * cnorm);

    for (int i = 0; i < nk; ++i) {
        uint32_t v = tk[t + (i << 8)];
        if (v >= keyT) {
            int idx = atomicAdd(&s_cnt, 1);
            if (idx < LISTCAP) s_list[idx] = t + (i << 8);
        }
    }
    __syncthreads();
    int cnt = s_cnt; if (cnt > LISTCAP) cnt = LISTCAP;
    const int total = cnt << gshift;

    // best = (dot, nsq, m); compare via signed-square cross-multiplication
    double bd = -1.0e300, bn = 1.0;
    double bp = bd * 1.0e300;   // -inf
    int bm = 0x7FFFFFFF;
    const float* cb = s_ctx + lane * 8;

    for (int base = w * 2; base < total; base += 8) {
        const bool has1 = (base + 1 < total);
        const int ia = base, ib = has1 ? base + 1 : base;
        const int ma = (s_list[ia >> gshift] << gshift) + (ia & gmask);
        const int mb = (s_list[ib >> gshift] << gshift) + (ib & gmask);
        double d0 = 0.0, n0 = 0.0, d1 = 0.0, n1 = 0.0;
        if (isbf) {
            uint4 va = *((const uint4*)((const uint16_t*)memv + (size_t)ma * D_DIM) + lane);
            uint4 vb = *((const uint4*)((const uint16_t*)memv + (size_t)mb * D_DIM) + lane);
            uint32_t wa[4] = {va.x, va.y, va.z, va.w};
            uint32_t wbv[4] = {vb.x, vb.y, vb.z, vb.w};
            #pragma unroll
            for (int i = 0; i < 4; ++i) {
                float a0 = __uint_as_float(wa[i] << 16);
                float a1 = __uint_as_float(wa[i] & 0xFFFF0000u);
                d0 += (double)a0 * (double)cb[2 * i];
                d0 += (double)a1 * (double)cb[2 * i + 1];
                n0 += (double)a0 * (double)a0 + (double)a1 * (double)a1;
                float b0v = __uint_as_float(wbv[i] << 16);
                float b1v = __uint_as_float(wbv[i] & 0xFFFF0000u);
                d1 += (double)b0v * (double)cb[2 * i];
                d1 += (double)b1v * (double)cb[2 * i + 1];
                n1 += (double)b0v * (double)b0v + (double)b1v * (double)b1v;
            }
        } else {
            const float4* pa = (const float4*)((const float*)memv + (size_t)ma * D_DIM) + lane * 2;
            const float4* pb = (const float4*)((const float*)memv + (size_t)mb * D_DIM) + lane * 2;
            float4 a0 = pa[0], a1 = pa[1], b0v = pb[0], b1v = pb[1];
            float xa[8] = {a0.x, a0.y, a0.z, a0.w, a1.x, a1.y, a1.z, a1.w};
            float xb[8] = {b0v.x, b0v.y, b0v.z, b0v.w, b1v.x, b1v.y, b1v.z, b1v.w};
            #pragma unroll
            for (int i = 0; i < 8; ++i) {
                d0 += (double)xa[i] * (double)cb[i];
                n0 += (double)xa[i] * (double)xa[i];
                d1 += (double)xb[i] * (double)cb[i];
                n1 += (double)xb[i] * (double)xb[i];
            }
        }
        #pragma unroll
        for (int o = 32; o; o >>= 1) {
            d0 += __shfl_xor(d0, o, 64);
            n0 += __shfl_xor(n0, o, 64);
            d1 += __shfl_xor(d1, o, 64);
            n1 += __shfl_xor(n1, o, 64);
        }
        double p0 = d0 * fabs(d0);
        double lhs = p0 * bn, rhs = bp * n0;
        if (lhs > rhs || (lhs == rhs && ma < bm)) { bd = d0; bn = n0; bp = p0; bm = ma; }
        if (has1) {
            double p1 = d1 * fabs(d1);
            double lhs1 = p1 * bn, rhs1 = bp * n1;
            if (lhs1 > rhs1 || (lhs1 == rhs1 && mb < bm)) { bd = d1; bn = n1; bp = p1; bm = mb; }
        }
    }
    if (lane == 0) { s_d[w] = bd; s_n[w] = bn; s_m[w] = bm; }
    __syncthreads();
    if (t == 0) {
        double cd = s_d[0], cn2 = s_n[0], cp = cd * fabs(cd);
        int cm = s_m[0];
        #pragma unroll
        for (int i = 1; i < 4; ++i) {
            double pd = s_d[i], pn = s_n[i], pp = pd * fabs(pd);
            double lhs = pp * cn2, rhs = cp * pn;
            if (lhs > rhs || (lhs == rhs && s_m[i] < cm)) { cd = pd; cn2 = pn; cp = pp; cm = s_m[i]; }
        }
        s_bestm = cm;
    }
    __syncthreads();
    const int mbest = s_bestm;
    if (isbf) {
        if (t < 64)
            ((uint4*)((uint16_t*)outv + (size_t)b * D_DIM))[t] =
                ((const uint4*)((const uint16_t*)memv + (size_t)mbest * D_DIM))[t];
    } else {
        if (t < 128)
            ((float4*)((float*)outv + (size_t)b * D_DIM))[t] =
                ((const float4*)((const float*)memv + (size_t)mbest * D_DIM))[t];
    }
}

extern "C" void kernel_launch(void* const* d_in, const int* in_sizes, int n_in,
                              void* d_out, int out_size, void* d_ws, size_t ws_size,
                              hipStream_t stream) {
    const void* ctx = d_in[0];
    const void* mem = d_in[1];
    if (in_sizes[0] > in_sizes[1]) { ctx = d_in[1]; mem = d_in[0]; }  // ctx is smaller

    const size_t fineBytes   = (size_t)B_CTX * 4096 * 4;   // 8 MB
    const size_t coarseBytes = (size_t)B_CTX * 512 * 4;    // 1 MB
    const size_t ctxBytes    = (size_t)B_CTX * D_DIM * 2;  // 0.5 MB
    const size_t memBytes    = (size_t)M_MEM * D_DIM * 2;  // 64 MB
    const size_t fastBytes   = fineBytes + 256 + ctxBytes + memBytes;  // ~72.5 MB

    if (ws_size >= fastBytes) {
        // fast path: one-pass convert+normalize, then triple-buffered counted-vmcnt GEMM
        uint32_t* tmax  = (uint32_t*)d_ws;
        uint32_t* flag  = (uint32_t*)((char*)d_ws + fineBytes);
        uint16_t* ctx_b = (uint16_t*)((char*)d_ws + fineBytes + 256);
        uint16_t* mem_s = (uint16_t*)((char*)d_ws + fineBytes + 256 + ctxBytes);
        dim3 grid(B_CTX / BBW, M_MEM / BM);    // (2, 512)
        detect_init<<<1, 64, 0, stream>>>((const uint32_t*)mem, flag);
        convert_scale<<<CVT_BLOCKS, 256, 0, stream>>>(ctx, mem, flag, mem_s, ctx_b);
        score_mfma<<<grid, 512, 0, stream>>>(mem_s, ctx_b, tmax, 0);
        phase2<<<B_CTX, 256, 0, stream>>>(ctx, mem, flag, tmax, d_out, 4096, 4);
    } else if (ws_size >= fineBytes + 256) {
        uint32_t* tmax = (uint32_t*)d_ws;
        uint32_t* flag = (uint32_t*)((char*)d_ws + fineBytes);
        dim3 grid(B_CTX / BB, M_MEM / BM);
        detect_init<<<1, 64, 0, stream>>>((const uint32_t*)mem, flag);
        score_phase1<<<grid, 256, 0, stream>>>(ctx, mem, flag, tmax, 0);
        phase2<<<B_CTX, 256, 0, stream>>>(ctx, mem, flag, tmax, d_out, 4096, 4);
    } else {
        uint32_t* tmax = (uint32_t*)d_ws;
        uint32_t* flag = (uint32_t*)((char*)d_ws + coarseBytes);
        dim3 grid(B_CTX / BB, M_MEM / BM);
        detect_init<<<1, 64, 0, stream>>>((const uint32_t*)mem, flag);
        score_phase1<<<grid, 256, 0, stream>>>(ctx, mem, flag, tmax, 1);
        phase2<<<B_CTX, 256, 0, stream>>>(ctx, mem, flag, tmax, d_out, 512, 7);
    }
}

// Round 8
// 263.471 us; speedup vs baseline: 1.0346x; 1.0132x over previous
//
#include <hip/hip_runtime.h>
#include <hip/hip_bf16.h>
#include <stdint.h>

#define D_DIM 512
#define B_CTX 512
#define M_MEM 65536
#define BM 128
#define BB 128               // legacy fallback tile
#define BBW 256              // fast-path ctx tile (512-thread blocks)
#define BK 32
#define GBK 32               // K-step of the fast bf16 GEMM
#define NIT (D_DIM / GBK)    // 16 K-steps
#define LDSPAD 40            // 80 B row pitch for legacy fallback kernel
#define DELTA_COS 2.5e-3f    // ~35 sigma of bf16 cosine noise, scale-invariant
#define LISTCAP 2048
#define CVT_MEM_BLOCKS (M_MEM / 32)            // 2048: 4 waves x 8 rows each
#define CVT_BLOCKS (CVT_MEM_BLOCKS + B_CTX / 32)

typedef __attribute__((ext_vector_type(8))) short short8;   // 8 bf16 (4 VGPR)
typedef __attribute__((ext_vector_type(4))) float floatx4;  // MFMA accumulator

__device__ __forceinline__ uint32_t f32_order(float s) {    // monotone f32->u32
    uint32_t u = __float_as_uint(s);
    return (u & 0x80000000u) ? ~u : (u | 0x80000000u);
}
__device__ __forceinline__ float f32_unorder(uint32_t v) {
    uint32_t u = (v & 0x80000000u) ? (v & 0x7FFFFFFFu) : ~v;
    return __uint_as_float(u);
}
__device__ __forceinline__ uint32_t pack_bf16_rtn(float a, float b) {
    uint32_t ua = __float_as_uint(a) + 0x8000u;
    uint32_t ub = __float_as_uint(b) + 0x8000u;
    return (ua >> 16) | (ub & 0xFFFF0000u);
}

// async global->LDS, 16B per lane. LDS dest is WAVE-UNIFORM base; HW adds lane*16.
typedef const __attribute__((address_space(1))) void gv_t;
typedef __attribute__((address_space(3))) void lv_t;
__device__ __forceinline__ void gload_lds16(const uint16_t* g, uint16_t* l) {
    __builtin_amdgcn_global_load_lds((gv_t*)g, (lv_t*)l, 16, 0, 0);
}

// in-block dtype probe: identical heuristic/data as detect_init -> identical
// verdict in every block (reads the same L2-hot 2KB of mem). t<64 participate.
__device__ __forceinline__ bool probe_isbf(const void* memv, int* s_bf, int t) {
    if (t == 0) *s_bf = 0;
    __syncthreads();
    if (t < 64) {
        int s = 0;
        #pragma unroll
        for (int i = 0; i < 8; ++i) {
            uint32_t u = ((const uint32_t*)memv)[t * 8 + i];
            uint32_t e = (u >> 7) & 0xFFu;   // exponent of LOW bf16 half
            s += (e >= 96u && e <= 144u) ? 1 : 0;
        }
        atomicAdd(s_bf, s);
    }
    __syncthreads();
    return (*s_bf > 256);
}

// ---------------- kernel 0 (fallback paths only): dtype probe ----------------
__global__ void detect_init(const uint32_t* __restrict__ mem_raw,
                            uint32_t* __restrict__ flag) {
    __shared__ int cnt;
    if (threadIdx.x == 0) cnt = 0;
    __syncthreads();
    int s = 0;
    #pragma unroll
    for (int i = 0; i < 8; ++i) {
        uint32_t u = mem_raw[threadIdx.x * 8 + i];
        uint32_t e = (u >> 7) & 0xFFu;
        s += (e >= 96u && e <= 144u) ? 1 : 0;
    }
    atomicAdd(&cnt, s);
    __syncthreads();
    if (threadIdx.x == 0) *flag = (cnt > 256) ? 1u : 0u;
}

// ---- kernel A: one-pass convert. mem -> bf16(mem * 1/|mem|), ctx -> bf16(ctx).
// Load-ALL-rows-first (16 loads in flight), then 8 independent reduce chains
// (ILP=8 across the shfl levels), then stores. Self-probes dtype (no flag). ----
__global__ __launch_bounds__(256) void convert_scale(const void* __restrict__ ctxv,
                                                     const void* __restrict__ memv,
                                                     uint16_t* __restrict__ mem_s,
                                                     uint16_t* __restrict__ ctx_b) {
    __shared__ int s_bf;
    const int t = threadIdx.x;
    const bool isbf = probe_isbf(memv, &s_bf, t);
    const int lane = t & 63;
    const int w = t >> 6;
    if (blockIdx.x < CVT_MEM_BLOCKS) {
        const int r0 = (blockIdx.x * 4 + w) * 8;     // 8 rows per wave
        float x[8][8];
        if (isbf) {
            #pragma unroll
            for (int i = 0; i < 8; ++i) {
                uint4 v = *((const uint4*)((const uint16_t*)memv + (size_t)(r0 + i) * D_DIM) + lane);
                uint32_t ww[4] = {v.x, v.y, v.z, v.w};
                #pragma unroll
                for (int j = 0; j < 4; ++j) {
                    x[i][2 * j]     = __uint_as_float(ww[j] << 16);
                    x[i][2 * j + 1] = __uint_as_float(ww[j] & 0xFFFF0000u);
                }
            }
        } else {
            #pragma unroll
            for (int i = 0; i < 8; ++i) {
                const float4* p = (const float4*)((const float*)memv + (size_t)(r0 + i) * D_DIM) + lane * 2;
                float4 a = p[0], bq = p[1];
                x[i][0] = a.x; x[i][1] = a.y; x[i][2] = a.z; x[i][3] = a.w;
                x[i][4] = bq.x; x[i][5] = bq.y; x[i][6] = bq.z; x[i][7] = bq.w;
            }
        }
        float nsq[8];
        #pragma unroll
        for (int i = 0; i < 8; ++i) {
            float s = 0.f;
            #pragma unroll
            for (int j = 0; j < 8; ++j) s = fmaf(x[i][j], x[i][j], s);
            nsq[i] = s;
        }
        #pragma unroll
        for (int o = 32; o; o >>= 1)
            #pragma unroll
            for (int i = 0; i < 8; ++i)
                nsq[i] += __shfl_xor(nsq[i], o, 64);
        #pragma unroll
        for (int i = 0; i < 8; ++i) {
            const float invn = rsqrtf(fmaxf(nsq[i], 1e-12f));
            uint4 ov;
            ov.x = pack_bf16_rtn(x[i][0] * invn, x[i][1] * invn);
            ov.y = pack_bf16_rtn(x[i][2] * invn, x[i][3] * invn);
            ov.z = pack_bf16_rtn(x[i][4] * invn, x[i][5] * invn);
            ov.w = pack_bf16_rtn(x[i][6] * invn, x[i][7] * invn);
            *((uint4*)(mem_s + (size_t)(r0 + i) * D_DIM) + lane) = ov;
        }
    } else {
        const int r0 = ((blockIdx.x - CVT_MEM_BLOCKS) * 4 + w) * 8;   // ctx rows
        #pragma unroll
        for (int i = 0; i < 8; ++i) {
            uint4 ov;
            if (isbf) {
                ov = *((const uint4*)((const uint16_t*)ctxv + (size_t)(r0 + i) * D_DIM) + lane);
            } else {
                const float4* p = (const float4*)((const float*)ctxv + (size_t)(r0 + i) * D_DIM) + lane * 2;
                float4 a = p[0], bq = p[1];
                ov.x = pack_bf16_rtn(a.x, a.y);
                ov.y = pack_bf16_rtn(a.z, a.w);
                ov.z = pack_bf16_rtn(bq.x, bq.y);
                ov.w = pack_bf16_rtn(bq.z, bq.w);
            }
            *((uint4*)(ctx_b + (size_t)(r0 + i) * D_DIM) + lane) = ov;
        }
    }
}

// ---- kernel B: pure-bf16 MFMA GEMM, triple-buffered counted-vmcnt (R7, best). ----
#define STAGE3(buf, kofs)                                                          \
    do {                                                                           \
        gload_lds16(ga  + (kofs), &at[buf][0][0] + (size_t)((w << 6)) * 8);        \
        gload_lds16(gb0 + (kofs), &bt[buf][0][0] + (size_t)((w << 6)) * 8);        \
        gload_lds16(gb1 + (kofs), &bt[buf][0][0] + (size_t)(512 + (w << 6)) * 8);  \
    } while (0)

__global__ __launch_bounds__(512, 4) void score_mfma(const uint16_t* __restrict__ A,   // mem_s [M][512]
                                                     const uint16_t* __restrict__ Bc,  // ctx_b [B][512]
                                                     uint32_t* __restrict__ tmax,
                                                     int coarse) {
    __shared__ __align__(16) uint16_t at[3][BM][GBK];    // 3 x 8KB, LINEAR dest
    __shared__ __align__(16) uint16_t bt[3][BBW][GBK];   // 3 x 16KB
    __shared__ uint32_t s_gbest[8][BBW];                 // 8KB -> 80KB, 2 blocks/CU

    const int h  = blockIdx.y * gridDim.x + blockIdx.x;   // 0..1023
    const int v  = (h & 7) * 128 + (h >> 3);              // bijective XCD-chunked remap
    const int bxp = v & 1;
    const int byp = v >> 1;

    const int t    = threadIdx.x;
    const int b0   = bxp * BBW;
    const int m0   = byp * BM;
    const int lane = t & 63;
    const int w    = t >> 6;
    const int wm   = w >> 2;
    const int wb   = w & 3;
    const int quad = lane >> 4;
    const int l15  = lane & 15;
    const int scol_sw = (((t & 3) ^ ((t >> 3) & 3)) << 3);   // T2 staging swizzle
    const int rc = ((quad ^ ((l15 >> 1) & 3)) << 3);         // T2 read swizzle

    const uint16_t* ga  = A  + (size_t)(m0 + (t >> 2)) * D_DIM + scol_sw;
    const uint16_t* gb0 = Bc + (size_t)(b0 + (t >> 2)) * D_DIM + scol_sw;
    const uint16_t* gb1 = gb0 + (size_t)128 * D_DIM;

    floatx4 acc[4][4];
    #pragma unroll
    for (int i = 0; i < 4; ++i)
        #pragma unroll
        for (int j = 0; j < 4; ++j)
            acc[i][j] = (floatx4){0.f, 0.f, 0.f, 0.f};

    STAGE3(0, 0);

    #pragma unroll
    for (int it = 0; it < NIT; ++it) {
        const int cur = it % 3;
        if (it < NIT - 1) STAGE3((it + 1) % 3, (it + 1) * GBK);
        if (it < NIT - 1) asm volatile("s_waitcnt vmcnt(3)" ::: "memory");
        else              asm volatile("s_waitcnt vmcnt(0)" ::: "memory");
        __builtin_amdgcn_sched_barrier(0);
        __builtin_amdgcn_s_barrier();
        __builtin_amdgcn_sched_barrier(0);

        short8 af[4], bg[4];
        #pragma unroll
        for (int i = 0; i < 4; ++i)
            af[i] = *(const short8*)&at[cur][wm * 64 + i * 16 + l15][rc];
        #pragma unroll
        for (int j = 0; j < 4; ++j)
            bg[j] = *(const short8*)&bt[cur][wb * 64 + j * 16 + l15][rc];
        __builtin_amdgcn_s_setprio(1);
        #pragma unroll
        for (int i = 0; i < 4; ++i)
            #pragma unroll
            for (int j = 0; j < 4; ++j)
                acc[i][j] = __builtin_amdgcn_mfma_f32_16x16x32_bf16(af[i], bg[j], acc[i][j], 0, 0, 0);
        __builtin_amdgcn_s_setprio(0);
    }

    #pragma unroll
    for (int i = 0; i < 4; ++i)
        #pragma unroll
        for (int j = 0; j < 4; ++j) {
            uint32_t k = 0;
            #pragma unroll
            for (int r = 0; r < 4; ++r) {
                uint32_t kk = f32_order(acc[i][j][r]);   // already cos * |ctx|
                k = kk > k ? kk : k;
            }
            uint32_t o1 = __shfl_xor(k, 16, 64); k = o1 > k ? o1 : k;
            uint32_t o2 = __shfl_xor(k, 32, 64); k = o2 > k ? o2 : k;
            if (quad == 0) s_gbest[wm * 4 + i][wb * 64 + j * 16 + l15] = k;
        }
    __syncthreads();

    if (!coarse) {
        const int G0 = byp * 8;
        for (int e = t; e < 8 * BBW; e += 512) {
            const int col = e >> 3, g = e & 7;
            tmax[(size_t)(b0 + col) * 4096 + G0 + g] = s_gbest[g][col];
        }
    } else {
        if (t < BBW) {
            uint32_t k = s_gbest[0][t];
            #pragma unroll
            for (int g = 1; g < 8; ++g) k = s_gbest[g][t] > k ? s_gbest[g][t] : k;
            tmax[(size_t)(b0 + t) * 512 + byp] = k;
        }
    }
}

// ---- legacy kernel 1 (fallback when workspace too small for bf16 copies) ----
__global__ __launch_bounds__(256) void score_phase1(const void* __restrict__ ctxv,
                                                    const void* __restrict__ memv,
                                                    const uint32_t* __restrict__ flag,
                                                    uint32_t* __restrict__ tmax,
                                                    int coarse) {
    __shared__ __align__(16) uint16_t at[BM][LDSPAD];
    __shared__ __align__(16) uint16_t bt[BB][LDSPAD];
    __shared__ float s_nsq[BM];
    __shared__ uint32_t s_gbest[8][BB];

    const int t    = threadIdx.x;
    const int b0   = blockIdx.x * BB;
    const int m0   = blockIdx.y * BM;
    const int lane = t & 63;
    const int w    = t >> 6;
    const int wm   = w >> 1;
    const int wb   = w & 1;
    const int quad = lane >> 4;
    const int l15  = lane & 15;
    const int srow = t >> 2;
    const int scol = (t & 3) * 8;

    floatx4 acc[4][4];
    #pragma unroll
    for (int i = 0; i < 4; ++i)
        #pragma unroll
        for (int j = 0; j < 4; ++j)
            acc[i][j] = (floatx4){0.f, 0.f, 0.f, 0.f};

    float nsq0 = 0.f, nsq1 = 0.f;
    const bool isbf = (*flag != 0u);

    for (int k0 = 0; k0 < D_DIM; k0 += BK) {
        __syncthreads();
        if (isbf) {
            const uint16_t* mp = (const uint16_t*)memv;
            const uint16_t* cp = (const uint16_t*)ctxv;
            uint4 va0 = *(const uint4*)(mp + (size_t)(m0 + srow) * D_DIM + k0 + scol);
            uint4 va1 = *(const uint4*)(mp + (size_t)(m0 + srow + 64) * D_DIM + k0 + scol);
            uint4 vb0 = *(const uint4*)(cp + (size_t)(b0 + srow) * D_DIM + k0 + scol);
            uint4 vb1 = *(const uint4*)(cp + (size_t)(b0 + srow + 64) * D_DIM + k0 + scol);
            *(uint4*)&at[srow][scol] = va0;
            *(uint4*)&at[srow + 64][scol] = va1;
            *(uint4*)&bt[srow][scol] = vb0;
            *(uint4*)&bt[srow + 64][scol] = vb1;
            uint32_t wa0[4] = {va0.x, va0.y, va0.z, va0.w};
            uint32_t wa1[4] = {va1.x, va1.y, va1.z, va1.w};
            #pragma unroll
            for (int i = 0; i < 4; ++i) {
                float a = __uint_as_float(wa0[i] << 16);
                float b = __uint_as_float(wa0[i] & 0xFFFF0000u);
                nsq0 = fmaf(a, a, nsq0); nsq0 = fmaf(b, b, nsq0);
                float c = __uint_as_float(wa1[i] << 16);
                float d = __uint_as_float(wa1[i] & 0xFFFF0000u);
                nsq1 = fmaf(c, c, nsq1); nsq1 = fmaf(d, d, nsq1);
            }
        } else {
            const float* mp = (const float*)memv;
            const float* cp = (const float*)ctxv;
            const float4* pa0 = (const float4*)(mp + (size_t)(m0 + srow) * D_DIM + k0 + scol);
            const float4* pa1 = (const float4*)(mp + (size_t)(m0 + srow + 64) * D_DIM + k0 + scol);
            const float4* pb0 = (const float4*)(cp + (size_t)(b0 + srow) * D_DIM + k0 + scol);
            const float4* pb1 = (const float4*)(cp + (size_t)(b0 + srow + 64) * D_DIM + k0 + scol);
            float4 a0 = pa0[0], a1 = pa0[1], a2 = pa1[0], a3 = pa1[1];
            float4 c0 = pb0[0], c1 = pb0[1], c2 = pb1[0], c3 = pb1[1];
            uint4 va0 = {pack_bf16_rtn(a0.x, a0.y), pack_bf16_rtn(a0.z, a0.w),
                         pack_bf16_rtn(a1.x, a1.y), pack_bf16_rtn(a1.z, a1.w)};
            uint4 va1 = {pack_bf16_rtn(a2.x, a2.y), pack_bf16_rtn(a2.z, a2.w),
                         pack_bf16_rtn(a3.x, a3.y), pack_bf16_rtn(a3.z, a3.w)};
            uint4 vb0 = {pack_bf16_rtn(c0.x, c0.y), pack_bf16_rtn(c0.z, c0.w),
                         pack_bf16_rtn(c1.x, c1.y), pack_bf16_rtn(c1.z, c1.w)};
            uint4 vb1 = {pack_bf16_rtn(c2.x, c2.y), pack_bf16_rtn(c2.z, c2.w),
                         pack_bf16_rtn(c3.x, c3.y), pack_bf16_rtn(c3.z, c3.w)};
            *(uint4*)&at[srow][scol] = va0;
            *(uint4*)&at[srow + 64][scol] = va1;
            *(uint4*)&bt[srow][scol] = vb0;
            *(uint4*)&bt[srow + 64][scol] = vb1;
            nsq0 = fmaf(a0.x, a0.x, nsq0); nsq0 = fmaf(a0.y, a0.y, nsq0);
            nsq0 = fmaf(a0.z, a0.z, nsq0); nsq0 = fmaf(a0.w, a0.w, nsq0);
            nsq0 = fmaf(a1.x, a1.x, nsq0); nsq0 = fmaf(a1.y, a1.y, nsq0);
            nsq0 = fmaf(a1.z, a1.z, nsq0); nsq0 = fmaf(a1.w, a1.w, nsq0);
            nsq1 = fmaf(a2.x, a2.x, nsq1); nsq1 = fmaf(a2.y, a2.y, nsq1);
            nsq1 = fmaf(a2.z, a2.z, nsq1); nsq1 = fmaf(a2.w, a2.w, nsq1);
            nsq1 = fmaf(a3.x, a3.x, nsq1); nsq1 = fmaf(a3.y, a3.y, nsq1);
            nsq1 = fmaf(a3.z, a3.z, nsq1); nsq1 = fmaf(a3.w, a3.w, nsq1);
        }
        __syncthreads();

        short8 af[4], bg[4];
        #pragma unroll
        for (int i = 0; i < 4; ++i)
            af[i] = *(const short8*)&at[wm * 64 + i * 16 + l15][quad * 8];
        #pragma unroll
        for (int j = 0; j < 4; ++j)
            bg[j] = *(const short8*)&bt[wb * 64 + j * 16 + l15][quad * 8];

        #pragma unroll
        for (int i = 0; i < 4; ++i)
            #pragma unroll
            for (int j = 0; j < 4; ++j)
                acc[i][j] = __builtin_amdgcn_mfma_f32_16x16x32_bf16(af[i], bg[j], acc[i][j], 0, 0, 0);
    }

    nsq0 += __shfl_xor(nsq0, 1, 64); nsq0 += __shfl_xor(nsq0, 2, 64);
    nsq1 += __shfl_xor(nsq1, 1, 64); nsq1 += __shfl_xor(nsq1, 2, 64);
    __syncthreads();
    if ((t & 3) == 0) { s_nsq[srow] = nsq0; s_nsq[srow + 64] = nsq1; }
    __syncthreads();

    float invn[4][4];
    #pragma unroll
    for (int i = 0; i < 4; ++i)
        #pragma unroll
        for (int r = 0; r < 4; ++r)
            invn[i][r] = rsqrtf(fmaxf(s_nsq[wm * 64 + i * 16 + quad * 4 + r], 1e-12f));

    #pragma unroll
    for (int i = 0; i < 4; ++i)
        #pragma unroll
        for (int j = 0; j < 4; ++j) {
            uint32_t k = 0;
            #pragma unroll
            for (int r = 0; r < 4; ++r) {
                uint32_t kk = f32_order(acc[i][j][r] * invn[i][r]);
                k = kk > k ? kk : k;
            }
            uint32_t o1 = __shfl_xor(k, 16, 64); k = o1 > k ? o1 : k;
            uint32_t o2 = __shfl_xor(k, 32, 64); k = o2 > k ? o2 : k;
            if (quad == 0) s_gbest[wm * 4 + i][wb * 64 + j * 16 + l15] = k;
        }
    __syncthreads();

    if (!coarse) {
        const int G0 = blockIdx.y * 8;
        for (int e = t; e < 8 * BB; e += 256) {
            const int col = e >> 3, g = e & 7;
            tmax[(size_t)(b0 + col) * 4096 + G0 + g] = s_gbest[g][col];
        }
    } else {
        if (t < BB) {
            uint32_t k = s_gbest[0][t];
            #pragma unroll
            for (int g = 1; g < 8; ++g) k = s_gbest[g][t] > k ? s_gbest[g][t] : k;
            tmax[(size_t)(b0 + t) * 512 + blockIdx.y] = k;
        }
    }
}

// ---- kernel 2: exact fp64 rescore + gather. Self-probes dtype. Key scans are
// compile-time unrolled into registers (kv[16]) -> one latency window, and the
// filter pass reuses registers instead of re-reading tmax. ----
__global__ __launch_bounds__(256) void phase2(const void* __restrict__ ctxv,
                                              const void* __restrict__ memv,
                                              const uint32_t* __restrict__ tmax,
                                              void* __restrict__ outv,
                                              int ngrp, int gshift) {
    __shared__ float s_ctx[D_DIM];
    __shared__ int s_list[LISTCAP];
    __shared__ int s_cnt;
    __shared__ int s_bf;
    __shared__ uint32_t s_red[4];
    __shared__ float s_cn[4];
    __shared__ double s_d[4], s_n[4];
    __shared__ int s_m[4];
    __shared__ int s_bestm;

    const int b = blockIdx.x;
    const int t = threadIdx.x;
    const int lane = t & 63;
    const int w = t >> 6;
    const int gmask = (1 << gshift) - 1;

    if (t == 0) s_cnt = 0;
    const bool isbf = probe_isbf(memv, &s_bf, t);

    if (isbf) {
        if (t < 64) {
            uint4 v = *((const uint4*)((const uint16_t*)ctxv + (size_t)b * D_DIM) + t);
            uint32_t ww[4] = {v.x, v.y, v.z, v.w};
            #pragma unroll
            for (int i = 0; i < 4; ++i) {
                s_ctx[t * 8 + 2 * i]     = __uint_as_float(ww[i] << 16);
                s_ctx[t * 8 + 2 * i + 1] = __uint_as_float(ww[i] & 0xFFFF0000u);
            }
        }
    } else {
        if (t < 128)
            ((float4*)s_ctx)[t] = ((const float4*)((const float*)ctxv + (size_t)b * D_DIM))[t];
    }
    __syncthreads();

    // ctx norm (scale-invariant rescan margin)
    float cs = s_ctx[t] * s_ctx[t] + s_ctx[t + 256] * s_ctx[t + 256];
    #pragma unroll
    for (int o = 32; o; o >>= 1) cs += __shfl_xor(cs, o, 64);
    if (lane == 0) s_cn[w] = cs;

    // key scan: compile-time-unrolled register loads (fine nk=16, coarse nk=2)
    const uint32_t* tk = tmax + (size_t)b * ngrp;
    uint32_t kv[16];
    uint32_t km = 0;
    const bool fine = (ngrp == 4096);
    if (fine) {
        #pragma unroll
        for (int i = 0; i < 16; ++i) kv[i] = tk[t + (i << 8)];
        #pragma unroll
        for (int i = 0; i < 16; ++i) km = kv[i] > km ? kv[i] : km;
    } else {
        #pragma unroll
        for (int i = 0; i < 2; ++i) kv[i] = tk[t + (i << 8)];
        km = kv[0] > kv[1] ? kv[0] : kv[1];
    }
    #pragma unroll
    for (int o = 32; o; o >>= 1) { uint32_t ot = __shfl_xor(km, o, 64); km = ot > km ? ot : km; }
    if (lane == 0) s_red[w] = km;
    __syncthreads();
    uint32_t kbest = s_red[0];
    #pragma unroll
    for (int i = 1; i < 4; ++i) kbest = s_red[i] > kbest ? s_red[i] : kbest;
    const float cnorm = sqrtf(s_cn[0] + s_cn[1] + s_cn[2] + s_cn[3]);
    const uint32_t keyT = f32_order(f32_unorder(kbest) - DELTA_COS * cnorm);

    if (fine) {
        #pragma unroll
        for (int i = 0; i < 16; ++i)
            if (kv[i] >= keyT) {
                int idx = atomicAdd(&s_cnt, 1);
                if (idx < LISTCAP) s_list[idx] = t + (i << 8);
            }
    } else {
        #pragma unroll
        for (int i = 0; i < 2; ++i)
            if (kv[i] >= keyT) {
                int idx = atomicAdd(&s_cnt, 1);
                if (idx < LISTCAP) s_list[idx] = t + (i << 8);
            }
    }
    __syncthreads();
    int cnt = s_cnt; if (cnt > LISTCAP) cnt = LISTCAP;
    const int total = cnt << gshift;

    // best = (dot, nsq, m); compare via signed-square cross-multiplication
    double bd = -1.0e300, bn = 1.0;
    double bp = bd * 1.0e300;   // -inf
    int bm = 0x7FFFFFFF;
    const float* cb = s_ctx + lane * 8;

    for (int base = w * 2; base < total; base += 8) {
        const bool has1 = (base + 1 < total);
        const int ia = base, ib = has1 ? base + 1 : base;
        const int ma = (s_list[ia >> gshift] << gshift) + (ia & gmask);
        const int mb = (s_list[ib >> gshift] << gshift) + (ib & gmask);
        double d0 = 0.0, n0 = 0.0, d1 = 0.0, n1 = 0.0;
        if (isbf) {
            uint4 va = *((const uint4*)((const uint16_t*)memv + (size_t)ma * D_DIM) + lane);
            uint4 vb = *((const uint4*)((const uint16_t*)memv + (size_t)mb * D_DIM) + lane);
            uint32_t wa[4] = {va.x, va.y, va.z, va.w};
            uint32_t wbv[4] = {vb.x, vb.y, vb.z, vb.w};
            #pragma unroll
            for (int i = 0; i < 4; ++i) {
                float a0 = __uint_as_float(wa[i] << 16);
                float a1 = __uint_as_float(wa[i] & 0xFFFF0000u);
                d0 += (double)a0 * (double)cb[2 * i];
                d0 += (double)a1 * (double)cb[2 * i + 1];
                n0 += (double)a0 * (double)a0 + (double)a1 * (double)a1;
                float b0v = __uint_as_float(wbv[i] << 16);
                float b1v = __uint_as_float(wbv[i] & 0xFFFF0000u);
                d1 += (double)b0v * (double)cb[2 * i];
                d1 += (double)b1v * (double)cb[2 * i + 1];
                n1 += (double)b0v * (double)b0v + (double)b1v * (double)b1v;
            }
        } else {
            const float4* pa = (const float4*)((const float*)memv + (size_t)ma * D_DIM) + lane * 2;
            const float4* pb = (const float4*)((const float*)memv + (size_t)mb * D_DIM) + lane * 2;
            float4 a0 = pa[0], a1 = pa[1], b0v = pb[0], b1v = pb[1];
            float xa[8] = {a0.x, a0.y, a0.z, a0.w, a1.x, a1.y, a1.z, a1.w};
            float xb[8] = {b0v.x, b0v.y, b0v.z, b0v.w, b1v.x, b1v.y, b1v.z, b1v.w};
            #pragma unroll
            for (int i = 0; i < 8; ++i) {
                d0 += (double)xa[i] * (double)cb[i];
                n0 += (double)xa[i] * (double)xa[i];
                d1 += (double)xb[i] * (double)cb[i];
                n1 += (double)xb[i] * (double)xb[i];
            }
        }
        #pragma unroll
        for (int o = 32; o; o >>= 1) {
            d0 += __shfl_xor(d0, o, 64);
            n0 += __shfl_xor(n0, o, 64);
            d1 += __shfl_xor(d1, o, 64);
            n1 += __shfl_xor(n1, o, 64);
        }
        double p0 = d0 * fabs(d0);
        double lhs = p0 * bn, rhs = bp * n0;
        if (lhs > rhs || (lhs == rhs && ma < bm)) { bd = d0; bn = n0; bp = p0; bm = ma; }
        if (has1) {
            double p1 = d1 * fabs(d1);
            double lhs1 = p1 * bn, rhs1 = bp * n1;
            if (lhs1 > rhs1 || (lhs1 == rhs1 && mb < bm)) { bd = d1; bn = n1; bp = p1; bm = mb; }
        }
    }
    if (lane == 0) { s_d[w] = bd; s_n[w] = bn; s_m[w] = bm; }
    __syncthreads();
    if (t == 0) {
        double cd = s_d[0], cn2 = s_n[0], cp = cd * fabs(cd);
        int cm = s_m[0];
        #pragma unroll
        for (int i = 1; i < 4; ++i) {
            double pd = s_d[i], pn = s_n[i], pp = pd * fabs(pd);
            double lhs = pp * cn2, rhs = cp * pn;
            if (lhs > rhs || (lhs == rhs && s_m[i] < cm)) { cd = pd; cn2 = pn; cp = pp; cm = s_m[i]; }
        }
        s_bestm = cm;
    }
    __syncthreads();
    const int mbest = s_bestm;
    if (isbf) {
        if (t < 64)
            ((uint4*)((uint16_t*)outv + (size_t)b * D_DIM))[t] =
                ((const uint4*)((const uint16_t*)memv + (size_t)mbest * D_DIM))[t];
    } else {
        if (t < 128)
            ((float4*)((float*)outv + (size_t)b * D_DIM))[t] =
                ((const float4*)((const float*)memv + (size_t)mbest * D_DIM))[t];
    }
}

extern "C" void kernel_launch(void* const* d_in, const int* in_sizes, int n_in,
                              void* d_out, int out_size, void* d_ws, size_t ws_size,
                              hipStream_t stream) {
    const void* ctx = d_in[0];
    const void* mem = d_in[1];
    if (in_sizes[0] > in_sizes[1]) { ctx = d_in[1]; mem = d_in[0]; }  // ctx is smaller

    const size_t fineBytes   = (size_t)B_CTX * 4096 * 4;   // 8 MB
    const size_t coarseBytes = (size_t)B_CTX * 512 * 4;    // 1 MB
    const size_t ctxBytes    = (size_t)B_CTX * D_DIM * 2;  // 0.5 MB
    const size_t memBytes    = (size_t)M_MEM * D_DIM * 2;  // 64 MB
    const size_t fastBytes   = fineBytes + 256 + ctxBytes + memBytes;  // ~72.5 MB

    if (ws_size >= fastBytes) {
        // fast path: 3 dispatches (convert+probe, GEMM, rescore+probe)
        uint32_t* tmax  = (uint32_t*)d_ws;
        uint16_t* ctx_b = (uint16_t*)((char*)d_ws + fineBytes + 256);
        uint16_t* mem_s = (uint16_t*)((char*)d_ws + fineBytes + 256 + ctxBytes);
        dim3 grid(B_CTX / BBW, M_MEM / BM);    // (2, 512)
        convert_scale<<<CVT_BLOCKS, 256, 0, stream>>>(ctx, mem, mem_s, ctx_b);
        score_mfma<<<grid, 512, 0, stream>>>(mem_s, ctx_b, tmax, 0);
        phase2<<<B_CTX, 256, 0, stream>>>(ctx, mem, tmax, d_out, 4096, 4);
    } else if (ws_size >= fineBytes + 256) {
        uint32_t* tmax = (uint32_t*)d_ws;
        uint32_t* flag = (uint32_t*)((char*)d_ws + fineBytes);
        dim3 grid(B_CTX / BB, M_MEM / BM);
        detect_init<<<1, 64, 0, stream>>>((const uint32_t*)mem, flag);
        score_phase1<<<grid, 256, 0, stream>>>(ctx, mem, flag, tmax, 0);
        phase2<<<B_CTX, 256, 0, stream>>>(ctx, mem, tmax, d_out, 4096, 4);
    } else {
        uint32_t* tmax = (uint32_t*)d_ws;
        uint32_t* flag = (uint32_t*)((char*)d_ws + coarseBytes);
        dim3 grid(B_CTX / BB, M_MEM / BM);
        detect_init<<<1, 64, 0, stream>>>((const uint32_t*)mem, flag);
        score_phase1<<<grid, 256, 0, stream>>>(ctx, mem, flag, tmax, 1);
        phase2<<<B_CTX, 256, 0, stream>>>(ctx, mem, tmax, d_out, 512, 7);
    }
}